// Round 20
// baseline (420.294 us; speedup 1.0000x reference)
//
#include <hip/hip_runtime.h>
#include <math.h>

// ---------------------------------------------------------------------------
// Mamba3DBlock forward. B=4, Npts=2048, C=384, K_GROUP=8. x rows = 8196.
// R19: launch-count reduction. std+cv+cls folded into knng's last block;
//      LN2 folded into GEMM2 via per-panel completion counters. 6 launches.
// ---------------------------------------------------------------------------

#define C384 384

typedef __attribute__((ext_vector_type(8))) short short8;
typedef __attribute__((ext_vector_type(4))) float f32x4;

__device__ __forceinline__ float gelu_exact(float v) {
    return 0.5f * v * (1.0f + erff(v * 0.7071067811865475f));
}

__device__ __forceinline__ unsigned short f2bf(float f) {
    unsigned u = __float_as_uint(f);
    u += 0x7fffu + ((u >> 16) & 1u);
    return (unsigned short)(u >> 16);
}

// ---------------- prep: LN1 + W1T(unscaled) + transposes + pts4 + cv + cnt0 --
// [0,2049) LN1 | [2049,2337) W1T | [2337,3633) w2/m1/m2 | [3633,3665) pts4
// [3665,3857) cv partials | 3857 zero counters
__global__ __launch_bounds__(256) void prep_kernel(const float* __restrict__ x,
                                                   const float* __restrict__ ln1g,
                                                   const float* __restrict__ ln1b,
                                                   float* __restrict__ xn,
                                                   const float* __restrict__ w1,
                                                   const float* __restrict__ w2,
                                                   const float* __restrict__ m1,
                                                   const float* __restrict__ m2,
                                                   const float* __restrict__ center,
                                                   const float* __restrict__ beta,
                                                   unsigned short* __restrict__ o1,
                                                   unsigned short* __restrict__ o2,
                                                   unsigned short* __restrict__ o3,
                                                   unsigned short* __restrict__ o4,
                                                   float4* __restrict__ pts,
                                                   float* __restrict__ cvpart,
                                                   int* __restrict__ cnts) {
    int tid = blockIdx.x;
    if (tid < 2049) {
        int w = threadIdx.x >> 6, l = threadIdx.x & 63;
        int row = tid * 4 + w;
        const float* xr = x + (size_t)row * C384;
        float v[6];
        float s = 0.f;
#pragma unroll
        for (int i = 0; i < 6; ++i) { v[i] = xr[l + 64 * i]; s += v[i]; }
#pragma unroll
        for (int off = 32; off; off >>= 1) s += __shfl_xor(s, off, 64);
        float m = s * (1.0f / 384.0f);
        float s2 = 0.f;
#pragma unroll
        for (int i = 0; i < 6; ++i) { v[i] -= m; s2 += v[i] * v[i]; }
#pragma unroll
        for (int off = 32; off; off >>= 1) s2 += __shfl_xor(s2, off, 64);
        float rstd = 1.0f / sqrtf(s2 * (1.0f / 384.0f) + 1e-5f);
#pragma unroll
        for (int i = 0; i < 6; ++i) {
            int c = l + 64 * i;
            xn[(size_t)row * C384 + c] = v[i] * rstd * ln1g[c] + ln1b[c];
        }
    } else if (tid < 2337) {
        int local = tid - 2049;              // 288 tiles: K=768 x N=384
        int kb = (local / 12) * 32, nb = (local % 12) * 32;
        __shared__ float tile[32][33];
        int c = threadIdx.x & 31, r0 = threadIdx.x >> 5;
#pragma unroll
        for (int i = 0; i < 4; ++i) {
            int r = r0 + i * 8;
            tile[r][c] = w1[(size_t)(kb + r) * 384 + nb + c];
        }
        __syncthreads();
#pragma unroll
        for (int i = 0; i < 4; ++i) {
            int r = r0 + i * 8;
            o1[(size_t)(nb + r) * 768 + kb + c] = f2bf(tile[c][r]);
        }
    } else if (tid < 3633) {
        int local = tid - 2337;
        const float* in; unsigned short* outp; int K, N;
        if (local < 144)      { in = w2; outp = o2; K = 384;  N = 384; }
        else if (local < 720) { in = m1; outp = o3; K = 384;  N = 1536; local -= 144; }
        else                  { in = m2; outp = o4; K = 1536; N = 384;  local -= 720; }
        int ntN = N >> 5;
        int kb = (local / ntN) * 32, nb = (local % ntN) * 32;
        __shared__ float tile[32][33];
        int c = threadIdx.x & 31, r0 = threadIdx.x >> 5;
#pragma unroll
        for (int i = 0; i < 4; ++i) {
            int r = r0 + i * 8;
            tile[r][c] = in[(size_t)(kb + r) * N + nb + c];
        }
        __syncthreads();
#pragma unroll
        for (int i = 0; i < 4; ++i) {
            int r = r0 + i * 8;
            outp[(size_t)(nb + r) * K + kb + c] = f2bf(tile[c][r]);
        }
    } else if (tid < 3665) {
        int p = (tid - 3633) * 256 + threadIdx.x;    // 0..8191
        float cx = center[p * 3], cy = center[p * 3 + 1], cz = center[p * 3 + 2];
        float sq = cx * cx + cy * cy + cz * cz;
        pts[p] = make_float4(cx, cy, cz, sq);
    } else if (tid < 3857) {
        int local = tid - 3665;                      // 0..191
        int nblk = local % 6, ks = local / 6;
        if (threadIdx.x < 64) {
            int n = nblk * 64 + threadIdx.x;
            float s = 0.f;
            int k0 = ks * 24;
#pragma unroll
            for (int j = 0; j < 24; ++j)
                s = fmaf(beta[k0 + j], w1[(size_t)(k0 + j) * 384 + n], s);
            cvpart[(size_t)ks * 384 + n] = s;
        }
    } else {
        if (threadIdx.x < 129) cnts[threadIdx.x] = 0;   // [0..127] gemm2, [128] knng
    }
}

// ---------------- KNN + gather fused; last block: std + cv + cls rows --------
__global__ __launch_bounds__(256) void knng_kernel(const float4* __restrict__ pts,
                                                   const float* __restrict__ xn,
                                                   const float* __restrict__ x,
                                                   const float* __restrict__ alpha,
                                                   const float* __restrict__ b1,
                                                   const float* __restrict__ cvpart,
                                                   const float* __restrict__ ln2g,
                                                   const float* __restrict__ ln2b,
                                                   unsigned short* __restrict__ efp,
                                                   float2* __restrict__ part,
                                                   float* __restrict__ stdbuf,
                                                   float* __restrict__ cv,
                                                   float* __restrict__ out,
                                                   unsigned short* __restrict__ yb,
                                                   int* __restrict__ cnts) {
    __shared__ int lastk;
    int w = threadIdx.x >> 6;
    int l = threadIdx.x & 63;
    int q = blockIdx.x * 4 + w;
    int b = q >> 11, n = q & 2047;
    __shared__ int sidx[4][8];
    {
        const float4* pb = pts + (size_t)b * 2048;
        float4 qp = pb[n];
        float sqq = qp.w;
        unsigned used = 0u;
        unsigned long long gv[8];
#pragma unroll
        for (int g = 0; g < 8; ++g) {
            unsigned long long kmin = ~0ULL;
#pragma unroll
            for (int j = 0; j < 4; ++j) {
                int i = g * 4 + j;
                float4 c = pb[i * 64 + l];
                float dot = qp.x * c.x + qp.y * c.y + qp.z * c.z;
                float d2 = (sqq + c.w) - 2.0f * dot;
                unsigned u = __float_as_uint(d2);
                u ^= (unsigned)(((int)u >> 31) | 0x80000000);
                unsigned long long kk = ((unsigned long long)u << 32) | (unsigned)i;
                kmin = kk < kmin ? kk : kmin;
            }
            gv[g] = kmin;
        }
        unsigned long long lm = gv[0];
#pragma unroll
        for (int g = 1; g < 8; ++g) lm = gv[g] < lm ? gv[g] : lm;

        for (int sel = 0; sel < 8; ++sel) {
            unsigned wval = (unsigned)(lm >> 32);
            unsigned wmin = wval;
#pragma unroll
            for (int off = 32; off; off >>= 1) {
                unsigned o = (unsigned)__shfl_xor((int)wmin, off, 64);
                wmin = o < wmin ? o : wmin;
            }
            bool eligible = (wval == wmin);
            unsigned long long mask = __ballot(eligible);
            unsigned myM = ((unsigned)lm) * 64u + (unsigned)l;
            if (__popcll(mask) > 1) {
                unsigned mc = eligible ? myM : 0xFFFFFFFFu;
#pragma unroll
                for (int off = 32; off; off >>= 1) {
                    unsigned o = (unsigned)__shfl_xor((int)mc, off, 64);
                    mc = o < mc ? o : mc;
                }
                eligible = eligible && (myM == mc);
            }
            if (eligible) {
                sidx[w][sel] = (int)myM;
                unsigned ws = (unsigned)lm;
                used |= (1u << ws);
                int g = ws >> 2;
                asm volatile("" ::: "memory");
                unsigned long long kmin = ~0ULL;
#pragma unroll
                for (int j = 0; j < 4; ++j) {
                    int i = g * 4 + j;
                    float4 c = pb[i * 64 + l];
                    float dot = qp.x * c.x + qp.y * c.y + qp.z * c.z;
                    float d2 = (sqq + c.w) - 2.0f * dot;
                    unsigned u = __float_as_uint(d2);
                    u ^= (unsigned)(((int)u >> 31) | 0x80000000);
                    u = (used & (1u << i)) ? 0xFFFFFFFFu : u;
                    unsigned long long kk = ((unsigned long long)u << 32) | (unsigned)i;
                    kmin = kk < kmin ? kk : kmin;
                }
                gv[g] = kmin;
                unsigned long long nlm = gv[0];
#pragma unroll
                for (int gg = 1; gg < 8; ++gg) nlm = gv[gg] < nlm ? gv[gg] : nlm;
                lm = nlm;
            }
        }
    }
    // gather phase
    const float* xno = xn + ((size_t)b * 2049 + 1) * C384;
    const float* xc  = xn + ((size_t)q + b + 1) * C384;
    int i0 = sidx[w][0], i1 = sidx[w][1], i2 = sidx[w][2], i3 = sidx[w][3];
    int i4 = sidx[w][4], i5 = sidx[w][5], i6 = sidx[w][6], i7 = sidx[w][7];
    float s1 = 0.f, s2 = 0.f;
#pragma unroll
    for (int ci = 0; ci < 6; ++ci) {
        int c = l + ci * 64;
        float xcv = xc[c];
        float v0 = xno[(size_t)i0 * C384 + c], v1 = xno[(size_t)i1 * C384 + c];
        float v2 = xno[(size_t)i2 * C384 + c], v3 = xno[(size_t)i3 * C384 + c];
        float v4 = xno[(size_t)i4 * C384 + c], v5 = xno[(size_t)i5 * C384 + c];
        float v6 = xno[(size_t)i6 * C384 + c], v7 = xno[(size_t)i7 * C384 + c];
        float acc = ((v0 + v1) + (v2 + v3)) + ((v4 + v5) + (v6 + v7));
        float d;
        d = v0 - xcv; s1 += d; s2 += d * d;
        d = v1 - xcv; s1 += d; s2 += d * d;
        d = v2 - xcv; s1 += d; s2 += d * d;
        d = v3 - xcv; s1 += d; s2 += d * d;
        d = v4 - xcv; s1 += d; s2 += d * d;
        d = v5 - xcv; s1 += d; s2 += d * d;
        d = v6 - xcv; s1 += d; s2 += d * d;
        d = v7 - xcv; s1 += d; s2 += d * d;
        float mk = acc * 0.125f;
        efp[(size_t)q * 768 + c]       = f2bf(alpha[c] * (mk - xcv));
        efp[(size_t)q * 768 + 384 + c] = f2bf(alpha[384 + c] * xcv);
    }
#pragma unroll
    for (int off = 32; off; off >>= 1) {
        s1 += __shfl_xor(s1, off, 64);
        s2 += __shfl_xor(s2, off, 64);
    }
    if (l == 0) part[q] = make_float2(s1, s2);

    // ---- last-block tail: std reduce + cv reduce + cls rows ----
    __threadfence();
    __syncthreads();
    int t = threadIdx.x;
    if (t == 0) {
        int old = atomicAdd(&cnts[128], 1);
        lastk = (old == 2047);
    }
    __syncthreads();
    if (!lastk) return;
    __threadfence();
    // std: f64 reduce of all 8192 partials (fixed order -> deterministic)
    {
        double d1 = 0.0, d2 = 0.0;
        for (int i = t; i < 8192; i += 256) {
            float2 p = part[i];
            d1 += (double)p.x;
            d2 += (double)p.y;
        }
        __shared__ double r1[256], r2[256];
        r1[t] = d1; r2[t] = d2;
        __syncthreads();
#pragma unroll
        for (int s = 128; s; s >>= 1) {
            if (t < s) { r1[t] += r1[t + s]; r2[t] += r2[t + s]; }
            __syncthreads();
        }
        if (t == 0) {
            const double N = 25165824.0;
            double var = (r2[0] - r1[0] * r1[0] / N) / (N - 1.0);
            float stdf = (float)sqrt(var);
            stdbuf[0] = 1.0f / (stdf + 1e-5f);
        }
    }
    // cv reduce
    for (int nn = t; nn < 384; nn += 256) {
        float s = b1[nn];
#pragma unroll
        for (int ks = 0; ks < 32; ++ks) s += cvpart[(size_t)ks * 384 + nn];
        cv[nn] = s;
    }
    // cls rows: out = x + xn; yb = LN2(out)
    {
        int row = w * 2049;                 // batch w cls row
        const float* xr = x + (size_t)row * C384;
        const float* xnr = xn + (size_t)row * C384;
        float v[6];
        float s = 0.f;
#pragma unroll
        for (int i = 0; i < 6; ++i) {
            int c = l + 64 * i;
            float o = xr[c] + xnr[c];
            out[(size_t)row * C384 + c] = o;
            v[i] = o;
            s += o;
        }
#pragma unroll
        for (int off = 32; off; off >>= 1) s += __shfl_xor(s, off, 64);
        float m = s * (1.0f / 384.0f);
        float s2s = 0.f;
#pragma unroll
        for (int i = 0; i < 6; ++i) { v[i] -= m; s2s += v[i] * v[i]; }
#pragma unroll
        for (int off = 32; off; off >>= 1) s2s += __shfl_xor(s2s, off, 64);
        float rstd = 1.0f / sqrtf(s2s * (1.0f / 384.0f) + 1e-5f);
#pragma unroll
        for (int i = 0; i < 6; ++i) {
            int c = l + 64 * i;
            yb[(size_t)row * C384 + c] = f2bf(v[i] * rstd * ln2g[c] + ln2b[c]);
        }
    }
}

// ---------------- bf16 MFMA GEMM, 64x64 tile, BK=64, global_load_lds ---------
// SCALEHALF: after K-tile 5, scale acc by inv=stdbuf[0].
// FUSELN2 (gemm2): per-M-panel counter; 6th finisher LN2s its 64 remapped
// rows from the completed out rows -> yb.
#define ST_STR 68

template <bool GELU, bool REMAP, bool RES, bool OUTBF, bool SCALEHALF, bool FUSELN2>
__global__ __launch_bounds__(256) void mfma_gemm(const unsigned short* __restrict__ A,
                                                 const unsigned short* __restrict__ Bt,
                                                 const float* __restrict__ bias,
                                                 const float* __restrict__ res,
                                                 const float* __restrict__ sb,
                                                 void* __restrict__ outp,
                                                 unsigned short* __restrict__ yb,
                                                 const float* __restrict__ lgw,
                                                 const float* __restrict__ lbw,
                                                 int* __restrict__ cnts,
                                                 int M, int N, int K, int ntn) {
    __shared__ char smem[32768];
    __shared__ int lastf;
    int t = threadIdx.x;
    int lane = t & 63, w = t >> 6;
    int wr = w >> 1, wc = w & 1;

    int nwg = gridDim.x;
    int q8 = nwg >> 3, r8 = nwg & 7;
    int xcd = blockIdx.x & 7, idx = blockIdx.x >> 3;
    int lid = (xcd < r8 ? xcd * (q8 + 1) : r8 * (q8 + 1) + (xcd - r8) * q8) + idx;
    int by = lid / ntn, bx = lid - by * ntn;
    int bm = by * 64, bn = bx * 64;

    float inv = SCALEHALF ? sb[0] : 1.0f;

    f32x4 acc[2][2] = {};

    const unsigned short* gbase[4];
    int lsegoff[4];
#pragma unroll
    for (int i = 0; i < 4; ++i) {
        int s = w * 4 + i;
        int row = (s & 7) * 8 + (lane >> 3);
        int cg = ((lane & 7) ^ (lane >> 3)) * 8;
        if (s < 8) {
            int gm = bm + row;
            if (gm > M - 1) gm = M - 1;
            gbase[i] = A + (size_t)gm * K + cg;
        } else {
            gbase[i] = Bt + (size_t)(bn + row) * K + cg;
        }
        lsegoff[i] = s * 1024;
    }

    auto issue = [&](int tile, int bufoff) {
        int ko = tile << 6;
#pragma unroll
        for (int i = 0; i < 4; ++i)
            __builtin_amdgcn_global_load_lds(
                (const __attribute__((address_space(1))) void*)(gbase[i] + ko),
                (__attribute__((address_space(3))) void*)(smem + bufoff + lsegoff[i]),
                16, 0, 0);
    };
    auto compute = [&](const char* smA) {
        const char* smB = smA + 8192;
#pragma unroll
        for (int ks = 0; ks < 2; ++ks) {
            short8 af[2], bfr[2];
            int cb = ks * 4 + (lane >> 4);
#pragma unroll
            for (int mi = 0; mi < 2; ++mi) {
                int row = wr * 32 + mi * 16 + (lane & 15);
                af[mi] = *(const short8*)(smA + row * 128 + ((cb ^ (row & 7)) << 4));
            }
#pragma unroll
            for (int nj = 0; nj < 2; ++nj) {
                int row = wc * 32 + nj * 16 + (lane & 15);
                bfr[nj] = *(const short8*)(smB + row * 128 + ((cb ^ (row & 7)) << 4));
            }
#pragma unroll
            for (int mi = 0; mi < 2; ++mi)
#pragma unroll
                for (int nj = 0; nj < 2; ++nj)
                    acc[mi][nj] = __builtin_amdgcn_mfma_f32_16x16x32_bf16(
                        af[mi], bfr[nj], acc[mi][nj], 0, 0, 0);
        }
    };

    int nt = K >> 6;
    issue(0, 0);
    __syncthreads();
    for (int tix = 0; tix < nt; ++tix) {
        if (tix + 1 < nt) issue(tix + 1, ((tix + 1) & 1) * 16384);
        compute(smem + (tix & 1) * 16384);
        if (SCALEHALF && tix == 5) {
#pragma unroll
            for (int mi = 0; mi < 2; ++mi)
#pragma unroll
                for (int nj = 0; nj < 2; ++nj)
                    acc[mi][nj] = acc[mi][nj] * inv;
        }
        __syncthreads();
    }

    float* st = (float*)smem;
#pragma unroll
    for (int nj = 0; nj < 2; ++nj) {
        int nl = wc * 32 + nj * 16 + (lane & 15);
        float bs = bias[bn + nl];
#pragma unroll
        for (int mi = 0; mi < 2; ++mi) {
#pragma unroll
            for (int r = 0; r < 4; ++r) {
                int ml = wr * 32 + mi * 16 + (lane >> 4) * 4 + r;
                float v = acc[mi][nj][r] + bs;
                if (GELU) v = gelu_exact(v);
                st[ml * ST_STR + nl] = v;
            }
        }
    }
    __syncthreads();
    if (OUTBF) {
#pragma unroll
        for (int i = 0; i < 2; ++i) {
            int chunk = t + i * 256;
            int ml = chunk >> 3, c8 = (chunk & 7) * 8;
            int m = bm + ml;
            if (m < M) {
                unsigned short tmp[8];
#pragma unroll
                for (int j = 0; j < 8; ++j) tmp[j] = f2bf(st[ml * ST_STR + c8 + j]);
                *(uint4*)((unsigned short*)outp + (size_t)m * N + bn + c8) = *(uint4*)tmp;
            }
        }
    } else {
#pragma unroll
        for (int i = 0; i < 4; ++i) {
            int chunk = t + i * 256;
            int ml = chunk >> 4, c4 = (chunk & 15) * 4;
            int m = bm + ml;
            if (m < M) {
                size_t orow = REMAP ? (size_t)(m + (m >> 11) + 1) : (size_t)m;
                size_t off = orow * (size_t)N + bn + c4;
                float4 v = *(float4*)&st[ml * ST_STR + c4];
                if (RES) {
                    float4 rv = *(const float4*)(res + off);
                    v.x += rv.x; v.y += rv.y; v.z += rv.z; v.w += rv.w;
                }
                *(float4*)((float*)outp + off) = v;
            }
        }
    }

    // ---- FUSELN2 tail: 6th finisher of panel `by` LN2s its 64 rows ----
    if (FUSELN2) {
        __threadfence();
        __syncthreads();
        if (t == 0) {
            int old = atomicAdd(&cnts[by], 1);
            lastf = (old == 5);
        }
        __syncthreads();
        if (lastf) {
            __threadfence();
#pragma unroll 1
            for (int i = 0; i < 16; ++i) {
                int m = bm + w * 16 + i;
                size_t orow = (size_t)(m + (m >> 11) + 1);
                const float* src = (const float*)outp + orow * C384;
                float v[6];
                float s = 0.f;
#pragma unroll
                for (int j = 0; j < 6; ++j) { v[j] = src[lane + 64 * j]; s += v[j]; }
#pragma unroll
                for (int off = 32; off; off >>= 1) s += __shfl_xor(s, off, 64);
                float mm = s * (1.0f / 384.0f);
                float s2 = 0.f;
#pragma unroll
                for (int j = 0; j < 6; ++j) { v[j] -= mm; s2 += v[j] * v[j]; }
#pragma unroll
                for (int off = 32; off; off >>= 1) s2 += __shfl_xor(s2, off, 64);
                float rstd = 1.0f / sqrtf(s2 * (1.0f / 384.0f) + 1e-5f);
#pragma unroll
                for (int j = 0; j < 6; ++j) {
                    int c = lane + 64 * j;
                    yb[orow * C384 + c] = f2bf(v[j] * rstd * lgw[c] + lbw[c]);
                }
            }
        }
    }
}

// ---------------------------------------------------------------------------
extern "C" void kernel_launch(void* const* d_in, const int* in_sizes, int n_in,
                              void* d_out, int out_size, void* d_ws, size_t ws_size,
                              hipStream_t stream) {
    const float* center  = (const float*)d_in[0];
    const float* x       = (const float*)d_in[1];
    const float* ln1_g   = (const float*)d_in[2];
    const float* ln1_b   = (const float*)d_in[3];
    const float* alpha   = (const float*)d_in[4];
    const float* beta    = (const float*)d_in[5];
    const float* attn_w1 = (const float*)d_in[6];
    const float* attn_b1 = (const float*)d_in[7];
    const float* attn_w2 = (const float*)d_in[8];
    const float* attn_b2 = (const float*)d_in[9];
    const float* ln2_g   = (const float*)d_in[10];
    const float* ln2_b   = (const float*)d_in[11];
    const float* mlp_w1  = (const float*)d_in[12];
    const float* mlp_b1  = (const float*)d_in[13];
    const float* mlp_w2  = (const float*)d_in[14];
    const float* mlp_b2  = (const float*)d_in[15];
    float* out = (float*)d_out;

    // workspace layout (bytes; g overlays dead xn/efp region)
    char* wsb = (char*)d_ws;
    float*          xn     = (float*)(wsb + 0);                  // 12,589,056 (prep->gemm2 tail)
    unsigned short* efp    = (unsigned short*)(wsb + 12589056);  // 12,582,912 (knng->gemm1)
    float2*         part   = (float2*)(wsb + 25434112);          // 65,536
    float*          stdbuf = (float*)(wsb + 25499648);           // 256
    float4*         pts4   = (float4*)(wsb + 25499904);          // 131,072
    float*          cv     = (float*)(wsb + 25630976);           // 1,536
    unsigned short* h1     = (unsigned short*)(wsb + 25632512);  // 6,291,456 (gemm1->gemm2)
    unsigned short* yb     = (unsigned short*)(wsb + 31923968);  // 6,294,528 (->gemm3)
    unsigned short* g      = (unsigned short*)(wsb + 0);         // 25,178,112 overlay (gemm3->gemm4)
    unsigned short* w1T    = (unsigned short*)(wsb + 38218496);  // 589,824
    unsigned short* w2T    = (unsigned short*)(wsb + 38808320);  // 294,912
    unsigned short* mw1T   = (unsigned short*)(wsb + 39103232);  // 1,179,648
    unsigned short* mw2T   = (unsigned short*)(wsb + 40282880);  // 1,179,648
    float*          cvpart = (float*)(wsb + 41462528);           // 49,152
    int*            cnts   = (int*)(wsb + 41511680);             // 129 ints

    // 0. prep: LN1 + W1T + transposes + pts4 + cv partials + counter zero
    prep_kernel<<<3858, 256, 0, stream>>>(x, ln1_g, ln1_b, xn, attn_w1,
                                          attn_w2, mlp_w1, mlp_w2, center, beta,
                                          w1T, w2T, mw1T, mw2T, pts4, cvpart, cnts);
    // 1. KNN + gather fused; last block: std + cv + cls rows
    knng_kernel<<<2048, 256, 0, stream>>>(pts4, xn, x, alpha, attn_b1, cvpart,
                                          ln2_g, ln2_b, efp, part, stdbuf, cv,
                                          out, yb, cnts);
    // 2. h1 = gelu(inv*(ef1@W1a) + ef2@W1b + cv)  M=8192 N=384 K=768
    mfma_gemm<true, false, false, true, true, false><<<768, 256, 0, stream>>>(
        efp, w1T, cv, nullptr, stdbuf, h1, nullptr, nullptr, nullptr, nullptr,
        8192, 384, 768, 6);
    // 3. out[remap] = x + h1 @ w2T + b2; 6th panel finisher does LN2 -> yb
    mfma_gemm<false, true, true, false, false, true><<<768, 256, 0, stream>>>(
        h1, w2T, attn_b2, x, nullptr, out, yb, ln2_g, ln2_b, cnts,
        8192, 384, 384, 6);
    // 4. g = gelu(yb @ mw1T + b1)                 M=8196 N=1536 K=384
    mfma_gemm<true, false, false, true, false, false><<<3096, 256, 0, stream>>>(
        yb, mw1T, mlp_b1, nullptr, nullptr, g, nullptr, nullptr, nullptr, nullptr,
        8196, 1536, 384, 24);
    // 5. out += g @ mw2T + b2                     M=8196 N=384 K=1536
    mfma_gemm<false, false, true, false, false, false><<<774, 256, 0, stream>>>(
        g, mw2T, mlp_b2, out, nullptr, out, nullptr, nullptr, nullptr, nullptr,
        8196, 384, 1536, 6);
}

// Round 21
// 126.380 us; speedup vs baseline: 3.3256x; 3.3256x over previous
//
#include <hip/hip_runtime.h>
#include <math.h>

// ---------------------------------------------------------------------------
// Mamba3DBlock forward. B=4, Npts=2048, C=384, K_GROUP=8. x rows = 8196.
// R20: full revert to R17 (best: 126.5us). R19's cooperative tails poisoned
//      the caches via per-block device-scope fences (knng 16->248us).
//      R17 = knng fusion + tcastw1 deletion (inv in GEMM1) + 8 launches.
// ---------------------------------------------------------------------------

#define C384 384

typedef __attribute__((ext_vector_type(8))) short short8;
typedef __attribute__((ext_vector_type(4))) float f32x4;

__device__ __forceinline__ float gelu_exact(float v) {
    return 0.5f * v * (1.0f + erff(v * 0.7071067811865475f));
}

__device__ __forceinline__ unsigned short f2bf(float f) {
    unsigned u = __float_as_uint(f);
    u += 0x7fffu + ((u >> 16) & 1u);
    return (unsigned short)(u >> 16);
}

// ---------------- prep: LN1 + W1T(unscaled) + transposes + pts4 + cv ---------
__global__ __launch_bounds__(256) void prep_kernel(const float* __restrict__ x,
                                                   const float* __restrict__ ln1g,
                                                   const float* __restrict__ ln1b,
                                                   float* __restrict__ xn,
                                                   const float* __restrict__ w1,
                                                   const float* __restrict__ w2,
                                                   const float* __restrict__ m1,
                                                   const float* __restrict__ m2,
                                                   const float* __restrict__ center,
                                                   const float* __restrict__ beta,
                                                   unsigned short* __restrict__ o1,
                                                   unsigned short* __restrict__ o2,
                                                   unsigned short* __restrict__ o3,
                                                   unsigned short* __restrict__ o4,
                                                   float4* __restrict__ pts,
                                                   float* __restrict__ cvpart) {
    int tid = blockIdx.x;
    if (tid < 2049) {
        int w = threadIdx.x >> 6, l = threadIdx.x & 63;
        int row = tid * 4 + w;
        const float* xr = x + (size_t)row * C384;
        float v[6];
        float s = 0.f;
#pragma unroll
        for (int i = 0; i < 6; ++i) { v[i] = xr[l + 64 * i]; s += v[i]; }
#pragma unroll
        for (int off = 32; off; off >>= 1) s += __shfl_xor(s, off, 64);
        float m = s * (1.0f / 384.0f);
        float s2 = 0.f;
#pragma unroll
        for (int i = 0; i < 6; ++i) { v[i] -= m; s2 += v[i] * v[i]; }
#pragma unroll
        for (int off = 32; off; off >>= 1) s2 += __shfl_xor(s2, off, 64);
        float rstd = 1.0f / sqrtf(s2 * (1.0f / 384.0f) + 1e-5f);
#pragma unroll
        for (int i = 0; i < 6; ++i) {
            int c = l + 64 * i;
            xn[(size_t)row * C384 + c] = v[i] * rstd * ln1g[c] + ln1b[c];
        }
    } else if (tid < 2337) {
        // W1 transpose+cast (UNSCALED; inv applied in GEMM1 via SCALEHALF)
        int local = tid - 2049;              // 288 tiles: K=768 x N=384
        int kb = (local / 12) * 32, nb = (local % 12) * 32;
        __shared__ float tile[32][33];
        int c = threadIdx.x & 31, r0 = threadIdx.x >> 5;
#pragma unroll
        for (int i = 0; i < 4; ++i) {
            int r = r0 + i * 8;
            tile[r][c] = w1[(size_t)(kb + r) * 384 + nb + c];
        }
        __syncthreads();
#pragma unroll
        for (int i = 0; i < 4; ++i) {
            int r = r0 + i * 8;
            o1[(size_t)(nb + r) * 768 + kb + c] = f2bf(tile[c][r]);
        }
    } else if (tid < 3633) {
        int local = tid - 2337;
        const float* in; unsigned short* outp; int K, N;
        if (local < 144)      { in = w2; outp = o2; K = 384;  N = 384; }
        else if (local < 720) { in = m1; outp = o3; K = 384;  N = 1536; local -= 144; }
        else                  { in = m2; outp = o4; K = 1536; N = 384;  local -= 720; }
        int ntN = N >> 5;
        int kb = (local / ntN) * 32, nb = (local % ntN) * 32;
        __shared__ float tile[32][33];
        int c = threadIdx.x & 31, r0 = threadIdx.x >> 5;
#pragma unroll
        for (int i = 0; i < 4; ++i) {
            int r = r0 + i * 8;
            tile[r][c] = in[(size_t)(kb + r) * N + nb + c];
        }
        __syncthreads();
#pragma unroll
        for (int i = 0; i < 4; ++i) {
            int r = r0 + i * 8;
            outp[(size_t)(nb + r) * K + kb + c] = f2bf(tile[c][r]);
        }
    } else if (tid < 3665) {
        int p = (tid - 3633) * 256 + threadIdx.x;    // 0..8191
        float cx = center[p * 3], cy = center[p * 3 + 1], cz = center[p * 3 + 2];
        float sq = cx * cx + cy * cy + cz * cz;
        pts[p] = make_float4(cx, cy, cz, sq);
    } else {
        int local = tid - 3665;                      // 0..191
        int nblk = local % 6, ks = local / 6;
        if (threadIdx.x < 64) {
            int n = nblk * 64 + threadIdx.x;
            float s = 0.f;
            int k0 = ks * 24;
#pragma unroll
            for (int j = 0; j < 24; ++j)
                s = fmaf(beta[k0 + j], w1[(size_t)(k0 + j) * 384 + n], s);
            cvpart[(size_t)ks * 384 + n] = s;
        }
    }
}

// ---------------- std (block 0) + cv reduce (block 1) ------------------------
__global__ __launch_bounds__(256) void std_kernel(const float2* __restrict__ part,
                                                  float* __restrict__ stdbuf,
                                                  const float* __restrict__ cvpart,
                                                  const float* __restrict__ b1,
                                                  float* __restrict__ cv) {
    int t = threadIdx.x;
    if (blockIdx.x == 1) {
        for (int n = t; n < 384; n += 256) {
            float s = b1[n];
#pragma unroll
            for (int ks = 0; ks < 32; ++ks) s += cvpart[(size_t)ks * 384 + n];
            cv[n] = s;
        }
        return;
    }
    double s1 = 0.0, s2 = 0.0;
    for (int i = t; i < 8192; i += 256) {
        float2 p = part[i];
        s1 += (double)p.x;
        s2 += (double)p.y;
    }
    __shared__ double r1[256], r2[256];
    r1[t] = s1; r2[t] = s2;
    __syncthreads();
#pragma unroll
    for (int s = 128; s; s >>= 1) {
        if (t < s) { r1[t] += r1[t + s]; r2[t] += r2[t + s]; }
        __syncthreads();
    }
    if (t == 0) {
        const double N = 25165824.0;
        double var = (r2[0] - r1[0] * r1[0] / N) / (N - 1.0);
        float stdf = (float)sqrt(var);
        stdbuf[0] = 1.0f / (stdf + 1e-5f);
    }
}

// ---------------- LN2 (+cls fusion): bf16 out; cls rows get out=x+xn first ---
__global__ __launch_bounds__(256) void ln2_kernel(const float* __restrict__ x,
                                                  const float* __restrict__ xn,
                                                  float* __restrict__ out,
                                                  unsigned short* __restrict__ yb,
                                                  const float* __restrict__ gw,
                                                  const float* __restrict__ bw) {
    int w = threadIdx.x >> 6, l = threadIdx.x & 63;
    int row = blockIdx.x * 4 + w;
    float v[6];
    if ((row & 2047) == (row >> 11)) {      // row % 2049 == 0 for row < 4*2049
        const float* xr = x + (size_t)row * C384;
        const float* xnr = xn + (size_t)row * C384;
        float* orow = out + (size_t)row * C384;
#pragma unroll
        for (int i = 0; i < 6; ++i) {
            int c = l + 64 * i;
            float o = xr[c] + xnr[c];
            orow[c] = o;
            v[i] = o;
        }
    } else {
        const float* src = out + (size_t)row * C384;
#pragma unroll
        for (int i = 0; i < 6; ++i) v[i] = src[l + 64 * i];
    }
    float s = 0.f;
#pragma unroll
    for (int i = 0; i < 6; ++i) s += v[i];
#pragma unroll
    for (int off = 32; off; off >>= 1) s += __shfl_xor(s, off, 64);
    float m = s * (1.0f / 384.0f);
    float s2 = 0.f;
#pragma unroll
    for (int i = 0; i < 6; ++i) { v[i] -= m; s2 += v[i] * v[i]; }
#pragma unroll
    for (int off = 32; off; off >>= 1) s2 += __shfl_xor(s2, off, 64);
    float rstd = 1.0f / sqrtf(s2 * (1.0f / 384.0f) + 1e-5f);
#pragma unroll
    for (int i = 0; i < 6; ++i) {
        int c = l + 64 * i;
        yb[(size_t)row * C384 + c] = f2bf(v[i] * rstd * gw[c] + bw[c]);
    }
}

// ---------------- KNN + gather fused: wave computes top-8, then gathers ------
__global__ __launch_bounds__(256) void knng_kernel(const float4* __restrict__ pts,
                                                   const float* __restrict__ xn,
                                                   const float* __restrict__ alpha,
                                                   unsigned short* __restrict__ efp,
                                                   float2* __restrict__ part) {
    int w = threadIdx.x >> 6;
    int l = threadIdx.x & 63;
    int q = blockIdx.x * 4 + w;
    int b = q >> 11, n = q & 2047;
    __shared__ int sidx[4][8];
    {
        const float4* pb = pts + (size_t)b * 2048;
        float4 qp = pb[n];
        float sqq = qp.w;
        unsigned val[32];
        unsigned long long gv[8];
#pragma unroll
        for (int g = 0; g < 8; ++g) {
            unsigned long long kmin = ~0ULL;
#pragma unroll
            for (int j = 0; j < 4; ++j) {
                int i = g * 4 + j;
                float4 c = pb[i * 64 + l];
                float dot = qp.x * c.x + qp.y * c.y + qp.z * c.z;
                float d2 = (sqq + c.w) - 2.0f * dot;
                unsigned u = __float_as_uint(d2);
                u ^= (unsigned)(((int)u >> 31) | 0x80000000);
                val[i] = u;
                unsigned long long kk = ((unsigned long long)u << 32) | (unsigned)i;
                kmin = kk < kmin ? kk : kmin;
            }
            gv[g] = kmin;
        }
        unsigned long long lm = gv[0];
#pragma unroll
        for (int g = 1; g < 8; ++g) lm = gv[g] < lm ? gv[g] : lm;

        for (int sel = 0; sel < 8; ++sel) {
            unsigned wval = (unsigned)(lm >> 32);
            unsigned wmin = wval;
#pragma unroll
            for (int off = 32; off; off >>= 1) {
                unsigned o = (unsigned)__shfl_xor((int)wmin, off, 64);
                wmin = o < wmin ? o : wmin;
            }
            bool eligible = (wval == wmin);
            unsigned long long mask = __ballot(eligible);
            unsigned myM = ((unsigned)lm) * 64u + (unsigned)l;
            if (__popcll(mask) > 1) {
                unsigned mc = eligible ? myM : 0xFFFFFFFFu;
#pragma unroll
                for (int off = 32; off; off >>= 1) {
                    unsigned o = (unsigned)__shfl_xor((int)mc, off, 64);
                    mc = o < mc ? o : mc;
                }
                eligible = eligible && (myM == mc);
            }
            if (eligible) {
                sidx[w][sel] = (int)myM;
                unsigned ws = (unsigned)lm;
#pragma unroll
                for (int g = 0; g < 8; ++g) {
                    if (gv[g] == lm) {
                        asm volatile("" ::: "memory");
                        unsigned long long kmin = ~0ULL;
#pragma unroll
                        for (int j = 0; j < 4; ++j) {
                            int i = g * 4 + j;
                            unsigned v = ((unsigned)i == ws) ? 0xFFFFFFFFu : val[i];
                            val[i] = v;
                            unsigned long long kk = ((unsigned long long)v << 32) | (unsigned)i;
                            kmin = kk < kmin ? kk : kmin;
                        }
                        gv[g] = kmin;
                    }
                }
                unsigned long long nlm = gv[0];
#pragma unroll
                for (int g = 1; g < 8; ++g) nlm = gv[g] < nlm ? gv[g] : nlm;
                lm = nlm;
            }
        }
    }
    // gather phase (same wave reads its own sidx)
    const float* xno = xn + ((size_t)b * 2049 + 1) * C384;
    const float* xc  = xn + ((size_t)q + b + 1) * C384;
    int i0 = sidx[w][0], i1 = sidx[w][1], i2 = sidx[w][2], i3 = sidx[w][3];
    int i4 = sidx[w][4], i5 = sidx[w][5], i6 = sidx[w][6], i7 = sidx[w][7];
    float s1 = 0.f, s2 = 0.f;
#pragma unroll
    for (int ci = 0; ci < 6; ++ci) {
        int c = l + ci * 64;
        float xcv = xc[c];
        float v0 = xno[(size_t)i0 * C384 + c], v1 = xno[(size_t)i1 * C384 + c];
        float v2 = xno[(size_t)i2 * C384 + c], v3 = xno[(size_t)i3 * C384 + c];
        float v4 = xno[(size_t)i4 * C384 + c], v5 = xno[(size_t)i5 * C384 + c];
        float v6 = xno[(size_t)i6 * C384 + c], v7 = xno[(size_t)i7 * C384 + c];
        float acc = ((v0 + v1) + (v2 + v3)) + ((v4 + v5) + (v6 + v7));
        float d;
        d = v0 - xcv; s1 += d; s2 += d * d;
        d = v1 - xcv; s1 += d; s2 += d * d;
        d = v2 - xcv; s1 += d; s2 += d * d;
        d = v3 - xcv; s1 += d; s2 += d * d;
        d = v4 - xcv; s1 += d; s2 += d * d;
        d = v5 - xcv; s1 += d; s2 += d * d;
        d = v6 - xcv; s1 += d; s2 += d * d;
        d = v7 - xcv; s1 += d; s2 += d * d;
        float mk = acc * 0.125f;
        efp[(size_t)q * 768 + c]       = f2bf(alpha[c] * (mk - xcv));
        efp[(size_t)q * 768 + 384 + c] = f2bf(alpha[384 + c] * xcv);
    }
#pragma unroll
    for (int off = 32; off; off >>= 1) {
        s1 += __shfl_xor(s1, off, 64);
        s2 += __shfl_xor(s2, off, 64);
    }
    if (l == 0) part[q] = make_float2(s1, s2);
}

// ---------------- bf16 MFMA GEMM, 64x64 tile, BK=64, global_load_lds ---------
// SCALEHALF: after K-tile 5 (k<384 accumulated), scale acc by inv=stdbuf[0].
#define ST_STR 68

template <bool GELU, bool REMAP, bool RES, bool OUTBF, bool SCALEHALF>
__global__ __launch_bounds__(256) void mfma_gemm(const unsigned short* __restrict__ A,
                                                 const unsigned short* __restrict__ Bt,
                                                 const float* __restrict__ bias,
                                                 const float* __restrict__ res,
                                                 const float* __restrict__ sb,
                                                 void* __restrict__ outp,
                                                 int M, int N, int K, int ntn) {
    __shared__ char smem[32768];   // 2 bufs x (A 8K | B 8K)
    int t = threadIdx.x;
    int lane = t & 63, w = t >> 6;
    int wr = w >> 1, wc = w & 1;

    int nwg = gridDim.x;
    int q8 = nwg >> 3, r8 = nwg & 7;
    int xcd = blockIdx.x & 7, idx = blockIdx.x >> 3;
    int lid = (xcd < r8 ? xcd * (q8 + 1) : r8 * (q8 + 1) + (xcd - r8) * q8) + idx;
    int by = lid / ntn, bx = lid - by * ntn;
    int bm = by * 64, bn = bx * 64;

    float inv = SCALEHALF ? sb[0] : 1.0f;

    f32x4 acc[2][2] = {};

    const unsigned short* gbase[4];
    int lsegoff[4];
#pragma unroll
    for (int i = 0; i < 4; ++i) {
        int s = w * 4 + i;
        int row = (s & 7) * 8 + (lane >> 3);
        int cg = ((lane & 7) ^ (lane >> 3)) * 8;
        if (s < 8) {
            int gm = bm + row;
            if (gm > M - 1) gm = M - 1;
            gbase[i] = A + (size_t)gm * K + cg;
        } else {
            gbase[i] = Bt + (size_t)(bn + row) * K + cg;
        }
        lsegoff[i] = s * 1024;
    }

    auto issue = [&](int tile, int bufoff) {
        int ko = tile << 6;
#pragma unroll
        for (int i = 0; i < 4; ++i)
            __builtin_amdgcn_global_load_lds(
                (const __attribute__((address_space(1))) void*)(gbase[i] + ko),
                (__attribute__((address_space(3))) void*)(smem + bufoff + lsegoff[i]),
                16, 0, 0);
    };
    auto compute = [&](const char* smA) {
        const char* smB = smA + 8192;
#pragma unroll
        for (int ks = 0; ks < 2; ++ks) {
            short8 af[2], bfr[2];
            int cb = ks * 4 + (lane >> 4);
#pragma unroll
            for (int mi = 0; mi < 2; ++mi) {
                int row = wr * 32 + mi * 16 + (lane & 15);
                af[mi] = *(const short8*)(smA + row * 128 + ((cb ^ (row & 7)) << 4));
            }
#pragma unroll
            for (int nj = 0; nj < 2; ++nj) {
                int row = wc * 32 + nj * 16 + (lane & 15);
                bfr[nj] = *(const short8*)(smB + row * 128 + ((cb ^ (row & 7)) << 4));
            }
#pragma unroll
            for (int mi = 0; mi < 2; ++mi)
#pragma unroll
                for (int nj = 0; nj < 2; ++nj)
                    acc[mi][nj] = __builtin_amdgcn_mfma_f32_16x16x32_bf16(
                        af[mi], bfr[nj], acc[mi][nj], 0, 0, 0);
        }
    };

    int nt = K >> 6;
    issue(0, 0);
    __syncthreads();
    for (int tix = 0; tix < nt; ++tix) {
        if (tix + 1 < nt) issue(tix + 1, ((tix + 1) & 1) * 16384);
        compute(smem + (tix & 1) * 16384);
        if (SCALEHALF && tix == 5) {
#pragma unroll
            for (int mi = 0; mi < 2; ++mi)
#pragma unroll
                for (int nj = 0; nj < 2; ++nj)
                    acc[mi][nj] = acc[mi][nj] * inv;
        }
        __syncthreads();
    }

    float* st = (float*)smem;
#pragma unroll
    for (int nj = 0; nj < 2; ++nj) {
        int nl = wc * 32 + nj * 16 + (lane & 15);
        float bs = bias[bn + nl];
#pragma unroll
        for (int mi = 0; mi < 2; ++mi) {
#pragma unroll
            for (int r = 0; r < 4; ++r) {
                int ml = wr * 32 + mi * 16 + (lane >> 4) * 4 + r;
                float v = acc[mi][nj][r] + bs;
                if (GELU) v = gelu_exact(v);
                st[ml * ST_STR + nl] = v;
            }
        }
    }
    __syncthreads();
    if (OUTBF) {
#pragma unroll
        for (int i = 0; i < 2; ++i) {
            int chunk = t + i * 256;
            int ml = chunk >> 3, c8 = (chunk & 7) * 8;
            int m = bm + ml;
            if (m < M) {
                unsigned short tmp[8];
#pragma unroll
                for (int j = 0; j < 8; ++j) tmp[j] = f2bf(st[ml * ST_STR + c8 + j]);
                *(uint4*)((unsigned short*)outp + (size_t)m * N + bn + c8) = *(uint4*)tmp;
            }
        }
    } else {
#pragma unroll
        for (int i = 0; i < 4; ++i) {
            int chunk = t + i * 256;
            int ml = chunk >> 4, c4 = (chunk & 15) * 4;
            int m = bm + ml;
            if (m < M) {
                size_t orow = REMAP ? (size_t)(m + (m >> 11) + 1) : (size_t)m;
                size_t off = orow * (size_t)N + bn + c4;
                float4 v = *(float4*)&st[ml * ST_STR + c4];
                if (RES) {
                    float4 rv = *(const float4*)(res + off);
                    v.x += rv.x; v.y += rv.y; v.z += rv.z; v.w += rv.w;
                }
                *(float4*)((float*)outp + off) = v;
            }
        }
    }
}

// ---------------------------------------------------------------------------
extern "C" void kernel_launch(void* const* d_in, const int* in_sizes, int n_in,
                              void* d_out, int out_size, void* d_ws, size_t ws_size,
                              hipStream_t stream) {
    const float* center  = (const float*)d_in[0];
    const float* x       = (const float*)d_in[1];
    const float* ln1_g   = (const float*)d_in[2];
    const float* ln1_b   = (const float*)d_in[3];
    const float* alpha   = (const float*)d_in[4];
    const float* beta    = (const float*)d_in[5];
    const float* attn_w1 = (const float*)d_in[6];
    const float* attn_b1 = (const float*)d_in[7];
    const float* attn_w2 = (const float*)d_in[8];
    const float* attn_b2 = (const float*)d_in[9];
    const float* ln2_g   = (const float*)d_in[10];
    const float* ln2_b   = (const float*)d_in[11];
    const float* mlp_w1  = (const float*)d_in[12];
    const float* mlp_b1  = (const float*)d_in[13];
    const float* mlp_w2  = (const float*)d_in[14];
    const float* mlp_b2  = (const float*)d_in[15];
    float* out = (float*)d_out;

    // workspace layout (bytes; g overlays dead xn/efp region)
    char* wsb = (char*)d_ws;
    float*          xn     = (float*)(wsb + 0);                  // 12,589,056 (prep->ln2)
    unsigned short* efp    = (unsigned short*)(wsb + 12589056);  // 12,582,912 (knng->gemm1)
    float2*         part   = (float2*)(wsb + 25434112);          // 65,536
    float*          stdbuf = (float*)(wsb + 25499648);           // 256
    float4*         pts4   = (float4*)(wsb + 25499904);          // 131,072
    float*          cv     = (float*)(wsb + 25630976);           // 1,536
    unsigned short* h1     = (unsigned short*)(wsb + 25632512);  // 6,291,456 (gemm1->gemm2)
    unsigned short* yb     = (unsigned short*)(wsb + 31923968);  // 6,294,528 (ln2->gemm3)
    unsigned short* g      = (unsigned short*)(wsb + 0);         // 25,178,112 overlay (gemm3->gemm4)
    unsigned short* w1T    = (unsigned short*)(wsb + 38218496);  // 589,824
    unsigned short* w2T    = (unsigned short*)(wsb + 38808320);  // 294,912
    unsigned short* mw1T   = (unsigned short*)(wsb + 39103232);  // 1,179,648
    unsigned short* mw2T   = (unsigned short*)(wsb + 40282880);  // 1,179,648
    float*          cvpart = (float*)(wsb + 41462528);           // 49,152

    // 0. prep: LN1 + W1T + transposes + pts4 + cv partials (one grid)
    prep_kernel<<<3857, 256, 0, stream>>>(x, ln1_g, ln1_b, xn, attn_w1,
                                          attn_w2, mlp_w1, mlp_w2, center, beta,
                                          w1T, w2T, mw1T, mw2T, pts4, cvpart);
    // 1. KNN + gather fused
    knng_kernel<<<2048, 256, 0, stream>>>(pts4, xn, alpha, efp, part);
    // 2. std (block 0) + cv reduce (block 1)
    std_kernel<<<2, 256, 0, stream>>>(part, stdbuf, cvpart, attn_b1, cv);
    // 3. h1 = gelu(inv*(ef1@W1a) + ef2@W1b + cv)  M=8192 N=384 K=768
    mfma_gemm<true, false, false, true, true><<<768, 256, 0, stream>>>(
        efp, w1T, cv, nullptr, stdbuf, h1, 8192, 384, 768, 6);
    // 4. out[remap] = x + h1 @ w2T + b2           M=8192 N=384 K=384
    mfma_gemm<false, true, true, false, false><<<768, 256, 0, stream>>>(
        h1, w2T, attn_b2, x, nullptr, out, 8192, 384, 384, 6);
    // 5. LN2 (+cls fusion) -> yb bf16
    ln2_kernel<<<2049, 256, 0, stream>>>(x, xn, out, yb, ln2_g, ln2_b);
    // 6. g = gelu(yb @ mw1T + b1)                 M=8196 N=1536 K=384
    mfma_gemm<true, false, false, true, false><<<3096, 256, 0, stream>>>(
        yb, mw1T, mlp_b1, nullptr, nullptr, g, 8196, 1536, 384, 24);
    // 7. out += g @ mw2T + b2                     M=8196 N=384 K=1536
    mfma_gemm<false, false, true, false, false><<<774, 256, 0, stream>>>(
        g, mw2T, mlp_b2, out, nullptr, out, 8196, 384, 1536, 6);
}

// Round 22
// 125.601 us; speedup vs baseline: 3.3463x; 1.0062x over previous
//
#include <hip/hip_runtime.h>
#include <math.h>

// ---------------------------------------------------------------------------
// Mamba3DBlock forward. B=4, Npts=2048, C=384, K_GROUP=8. x rows = 8196.
// R21: R20 + bf16 xn copy (xnb) for the gather phase — halves gather's
//      ~100MB scattered read traffic. f32 xn kept for LN2 cls-row fusion.
// ---------------------------------------------------------------------------

#define C384 384

typedef __attribute__((ext_vector_type(8))) short short8;
typedef __attribute__((ext_vector_type(4))) float f32x4;

__device__ __forceinline__ float gelu_exact(float v) {
    return 0.5f * v * (1.0f + erff(v * 0.7071067811865475f));
}

__device__ __forceinline__ unsigned short f2bf(float f) {
    unsigned u = __float_as_uint(f);
    u += 0x7fffu + ((u >> 16) & 1u);
    return (unsigned short)(u >> 16);
}

__device__ __forceinline__ float bf2f(unsigned short b) {
    return __uint_as_float((unsigned)b << 16);
}

// ---------------- prep: LN1(+bf16 copy) + W1T + transposes + pts4 + cv -------
__global__ __launch_bounds__(256) void prep_kernel(const float* __restrict__ x,
                                                   const float* __restrict__ ln1g,
                                                   const float* __restrict__ ln1b,
                                                   float* __restrict__ xn,
                                                   unsigned short* __restrict__ xnb,
                                                   const float* __restrict__ w1,
                                                   const float* __restrict__ w2,
                                                   const float* __restrict__ m1,
                                                   const float* __restrict__ m2,
                                                   const float* __restrict__ center,
                                                   const float* __restrict__ beta,
                                                   unsigned short* __restrict__ o1,
                                                   unsigned short* __restrict__ o2,
                                                   unsigned short* __restrict__ o3,
                                                   unsigned short* __restrict__ o4,
                                                   float4* __restrict__ pts,
                                                   float* __restrict__ cvpart) {
    int tid = blockIdx.x;
    if (tid < 2049) {
        int w = threadIdx.x >> 6, l = threadIdx.x & 63;
        int row = tid * 4 + w;
        const float* xr = x + (size_t)row * C384;
        float v[6];
        float s = 0.f;
#pragma unroll
        for (int i = 0; i < 6; ++i) { v[i] = xr[l + 64 * i]; s += v[i]; }
#pragma unroll
        for (int off = 32; off; off >>= 1) s += __shfl_xor(s, off, 64);
        float m = s * (1.0f / 384.0f);
        float s2 = 0.f;
#pragma unroll
        for (int i = 0; i < 6; ++i) { v[i] -= m; s2 += v[i] * v[i]; }
#pragma unroll
        for (int off = 32; off; off >>= 1) s2 += __shfl_xor(s2, off, 64);
        float rstd = 1.0f / sqrtf(s2 * (1.0f / 384.0f) + 1e-5f);
#pragma unroll
        for (int i = 0; i < 6; ++i) {
            int c = l + 64 * i;
            float o = v[i] * rstd * ln1g[c] + ln1b[c];
            xn[(size_t)row * C384 + c] = o;
            xnb[(size_t)row * C384 + c] = f2bf(o);
        }
    } else if (tid < 2337) {
        // W1 transpose+cast (UNSCALED; inv applied in GEMM1 via SCALEHALF)
        int local = tid - 2049;              // 288 tiles: K=768 x N=384
        int kb = (local / 12) * 32, nb = (local % 12) * 32;
        __shared__ float tile[32][33];
        int c = threadIdx.x & 31, r0 = threadIdx.x >> 5;
#pragma unroll
        for (int i = 0; i < 4; ++i) {
            int r = r0 + i * 8;
            tile[r][c] = w1[(size_t)(kb + r) * 384 + nb + c];
        }
        __syncthreads();
#pragma unroll
        for (int i = 0; i < 4; ++i) {
            int r = r0 + i * 8;
            o1[(size_t)(nb + r) * 768 + kb + c] = f2bf(tile[c][r]);
        }
    } else if (tid < 3633) {
        int local = tid - 2337;
        const float* in; unsigned short* outp; int K, N;
        if (local < 144)      { in = w2; outp = o2; K = 384;  N = 384; }
        else if (local < 720) { in = m1; outp = o3; K = 384;  N = 1536; local -= 144; }
        else                  { in = m2; outp = o4; K = 1536; N = 384;  local -= 720; }
        int ntN = N >> 5;
        int kb = (local / ntN) * 32, nb = (local % ntN) * 32;
        __shared__ float tile[32][33];
        int c = threadIdx.x & 31, r0 = threadIdx.x >> 5;
#pragma unroll
        for (int i = 0; i < 4; ++i) {
            int r = r0 + i * 8;
            tile[r][c] = in[(size_t)(kb + r) * N + nb + c];
        }
        __syncthreads();
#pragma unroll
        for (int i = 0; i < 4; ++i) {
            int r = r0 + i * 8;
            outp[(size_t)(nb + r) * K + kb + c] = f2bf(tile[c][r]);
        }
    } else if (tid < 3665) {
        int p = (tid - 3633) * 256 + threadIdx.x;    // 0..8191
        float cx = center[p * 3], cy = center[p * 3 + 1], cz = center[p * 3 + 2];
        float sq = cx * cx + cy * cy + cz * cz;
        pts[p] = make_float4(cx, cy, cz, sq);
    } else {
        int local = tid - 3665;                      // 0..191
        int nblk = local % 6, ks = local / 6;
        if (threadIdx.x < 64) {
            int n = nblk * 64 + threadIdx.x;
            float s = 0.f;
            int k0 = ks * 24;
#pragma unroll
            for (int j = 0; j < 24; ++j)
                s = fmaf(beta[k0 + j], w1[(size_t)(k0 + j) * 384 + n], s);
            cvpart[(size_t)ks * 384 + n] = s;
        }
    }
}

// ---------------- std (block 0) + cv reduce (block 1) ------------------------
__global__ __launch_bounds__(256) void std_kernel(const float2* __restrict__ part,
                                                  float* __restrict__ stdbuf,
                                                  const float* __restrict__ cvpart,
                                                  const float* __restrict__ b1,
                                                  float* __restrict__ cv) {
    int t = threadIdx.x;
    if (blockIdx.x == 1) {
        for (int n = t; n < 384; n += 256) {
            float s = b1[n];
#pragma unroll
            for (int ks = 0; ks < 32; ++ks) s += cvpart[(size_t)ks * 384 + n];
            cv[n] = s;
        }
        return;
    }
    double s1 = 0.0, s2 = 0.0;
    for (int i = t; i < 8192; i += 256) {
        float2 p = part[i];
        s1 += (double)p.x;
        s2 += (double)p.y;
    }
    __shared__ double r1[256], r2[256];
    r1[t] = s1; r2[t] = s2;
    __syncthreads();
#pragma unroll
    for (int s = 128; s; s >>= 1) {
        if (t < s) { r1[t] += r1[t + s]; r2[t] += r2[t + s]; }
        __syncthreads();
    }
    if (t == 0) {
        const double N = 25165824.0;
        double var = (r2[0] - r1[0] * r1[0] / N) / (N - 1.0);
        float stdf = (float)sqrt(var);
        stdbuf[0] = 1.0f / (stdf + 1e-5f);
    }
}

// ---------------- LN2 (+cls fusion): bf16 out; cls rows get out=x+xn first ---
__global__ __launch_bounds__(256) void ln2_kernel(const float* __restrict__ x,
                                                  const float* __restrict__ xn,
                                                  float* __restrict__ out,
                                                  unsigned short* __restrict__ yb,
                                                  const float* __restrict__ gw,
                                                  const float* __restrict__ bw) {
    int w = threadIdx.x >> 6, l = threadIdx.x & 63;
    int row = blockIdx.x * 4 + w;
    float v[6];
    if ((row & 2047) == (row >> 11)) {      // row % 2049 == 0 for row < 4*2049
        const float* xr = x + (size_t)row * C384;
        const float* xnr = xn + (size_t)row * C384;
        float* orow = out + (size_t)row * C384;
#pragma unroll
        for (int i = 0; i < 6; ++i) {
            int c = l + 64 * i;
            float o = xr[c] + xnr[c];
            orow[c] = o;
            v[i] = o;
        }
    } else {
        const float* src = out + (size_t)row * C384;
#pragma unroll
        for (int i = 0; i < 6; ++i) v[i] = src[l + 64 * i];
    }
    float s = 0.f;
#pragma unroll
    for (int i = 0; i < 6; ++i) s += v[i];
#pragma unroll
    for (int off = 32; off; off >>= 1) s += __shfl_xor(s, off, 64);
    float m = s * (1.0f / 384.0f);
    float s2 = 0.f;
#pragma unroll
    for (int i = 0; i < 6; ++i) { v[i] -= m; s2 += v[i] * v[i]; }
#pragma unroll
    for (int off = 32; off; off >>= 1) s2 += __shfl_xor(s2, off, 64);
    float rstd = 1.0f / sqrtf(s2 * (1.0f / 384.0f) + 1e-5f);
#pragma unroll
    for (int i = 0; i < 6; ++i) {
        int c = l + 64 * i;
        yb[(size_t)row * C384 + c] = f2bf(v[i] * rstd * gw[c] + bw[c]);
    }
}

// ---------------- KNN + gather fused: gather reads bf16 xnb ------------------
__global__ __launch_bounds__(256) void knng_kernel(const float4* __restrict__ pts,
                                                   const unsigned short* __restrict__ xnb,
                                                   const float* __restrict__ alpha,
                                                   unsigned short* __restrict__ efp,
                                                   float2* __restrict__ part) {
    int w = threadIdx.x >> 6;
    int l = threadIdx.x & 63;
    int q = blockIdx.x * 4 + w;
    int b = q >> 11, n = q & 2047;
    __shared__ int sidx[4][8];
    {
        const float4* pb = pts + (size_t)b * 2048;
        float4 qp = pb[n];
        float sqq = qp.w;
        unsigned val[32];
        unsigned long long gv[8];
#pragma unroll
        for (int g = 0; g < 8; ++g) {
            unsigned long long kmin = ~0ULL;
#pragma unroll
            for (int j = 0; j < 4; ++j) {
                int i = g * 4 + j;
                float4 c = pb[i * 64 + l];
                float dot = qp.x * c.x + qp.y * c.y + qp.z * c.z;
                float d2 = (sqq + c.w) - 2.0f * dot;
                unsigned u = __float_as_uint(d2);
                u ^= (unsigned)(((int)u >> 31) | 0x80000000);
                val[i] = u;
                unsigned long long kk = ((unsigned long long)u << 32) | (unsigned)i;
                kmin = kk < kmin ? kk : kmin;
            }
            gv[g] = kmin;
        }
        unsigned long long lm = gv[0];
#pragma unroll
        for (int g = 1; g < 8; ++g) lm = gv[g] < lm ? gv[g] : lm;

        for (int sel = 0; sel < 8; ++sel) {
            unsigned wval = (unsigned)(lm >> 32);
            unsigned wmin = wval;
#pragma unroll
            for (int off = 32; off; off >>= 1) {
                unsigned o = (unsigned)__shfl_xor((int)wmin, off, 64);
                wmin = o < wmin ? o : wmin;
            }
            bool eligible = (wval == wmin);
            unsigned long long mask = __ballot(eligible);
            unsigned myM = ((unsigned)lm) * 64u + (unsigned)l;
            if (__popcll(mask) > 1) {
                unsigned mc = eligible ? myM : 0xFFFFFFFFu;
#pragma unroll
                for (int off = 32; off; off >>= 1) {
                    unsigned o = (unsigned)__shfl_xor((int)mc, off, 64);
                    mc = o < mc ? o : mc;
                }
                eligible = eligible && (myM == mc);
            }
            if (eligible) {
                sidx[w][sel] = (int)myM;
                unsigned ws = (unsigned)lm;
#pragma unroll
                for (int g = 0; g < 8; ++g) {
                    if (gv[g] == lm) {
                        asm volatile("" ::: "memory");
                        unsigned long long kmin = ~0ULL;
#pragma unroll
                        for (int j = 0; j < 4; ++j) {
                            int i = g * 4 + j;
                            unsigned v = ((unsigned)i == ws) ? 0xFFFFFFFFu : val[i];
                            val[i] = v;
                            unsigned long long kk = ((unsigned long long)v << 32) | (unsigned)i;
                            kmin = kk < kmin ? kk : kmin;
                        }
                        gv[g] = kmin;
                    }
                }
                unsigned long long nlm = gv[0];
#pragma unroll
                for (int g = 1; g < 8; ++g) nlm = gv[g] < nlm ? gv[g] : nlm;
                lm = nlm;
            }
        }
    }
    // gather phase (bf16 reads; math in f32)
    const unsigned short* xno = xnb + ((size_t)b * 2049 + 1) * C384;
    const unsigned short* xc  = xnb + ((size_t)q + b + 1) * C384;
    int i0 = sidx[w][0], i1 = sidx[w][1], i2 = sidx[w][2], i3 = sidx[w][3];
    int i4 = sidx[w][4], i5 = sidx[w][5], i6 = sidx[w][6], i7 = sidx[w][7];
    float s1 = 0.f, s2 = 0.f;
#pragma unroll
    for (int ci = 0; ci < 6; ++ci) {
        int c = l + ci * 64;
        float xcv = bf2f(xc[c]);
        float v0 = bf2f(xno[(size_t)i0 * C384 + c]), v1 = bf2f(xno[(size_t)i1 * C384 + c]);
        float v2 = bf2f(xno[(size_t)i2 * C384 + c]), v3 = bf2f(xno[(size_t)i3 * C384 + c]);
        float v4 = bf2f(xno[(size_t)i4 * C384 + c]), v5 = bf2f(xno[(size_t)i5 * C384 + c]);
        float v6 = bf2f(xno[(size_t)i6 * C384 + c]), v7 = bf2f(xno[(size_t)i7 * C384 + c]);
        float acc = ((v0 + v1) + (v2 + v3)) + ((v4 + v5) + (v6 + v7));
        float d;
        d = v0 - xcv; s1 += d; s2 += d * d;
        d = v1 - xcv; s1 += d; s2 += d * d;
        d = v2 - xcv; s1 += d; s2 += d * d;
        d = v3 - xcv; s1 += d; s2 += d * d;
        d = v4 - xcv; s1 += d; s2 += d * d;
        d = v5 - xcv; s1 += d; s2 += d * d;
        d = v6 - xcv; s1 += d; s2 += d * d;
        d = v7 - xcv; s1 += d; s2 += d * d;
        float mk = acc * 0.125f;
        efp[(size_t)q * 768 + c]       = f2bf(alpha[c] * (mk - xcv));
        efp[(size_t)q * 768 + 384 + c] = f2bf(alpha[384 + c] * xcv);
    }
#pragma unroll
    for (int off = 32; off; off >>= 1) {
        s1 += __shfl_xor(s1, off, 64);
        s2 += __shfl_xor(s2, off, 64);
    }
    if (l == 0) part[q] = make_float2(s1, s2);
}

// ---------------- bf16 MFMA GEMM, 64x64 tile, BK=64, global_load_lds ---------
// SCALEHALF: after K-tile 5 (k<384 accumulated), scale acc by inv=stdbuf[0].
#define ST_STR 68

template <bool GELU, bool REMAP, bool RES, bool OUTBF, bool SCALEHALF>
__global__ __launch_bounds__(256) void mfma_gemm(const unsigned short* __restrict__ A,
                                                 const unsigned short* __restrict__ Bt,
                                                 const float* __restrict__ bias,
                                                 const float* __restrict__ res,
                                                 const float* __restrict__ sb,
                                                 void* __restrict__ outp,
                                                 int M, int N, int K, int ntn) {
    __shared__ char smem[32768];   // 2 bufs x (A 8K | B 8K)
    int t = threadIdx.x;
    int lane = t & 63, w = t >> 6;
    int wr = w >> 1, wc = w & 1;

    int nwg = gridDim.x;
    int q8 = nwg >> 3, r8 = nwg & 7;
    int xcd = blockIdx.x & 7, idx = blockIdx.x >> 3;
    int lid = (xcd < r8 ? xcd * (q8 + 1) : r8 * (q8 + 1) + (xcd - r8) * q8) + idx;
    int by = lid / ntn, bx = lid - by * ntn;
    int bm = by * 64, bn = bx * 64;

    float inv = SCALEHALF ? sb[0] : 1.0f;

    f32x4 acc[2][2] = {};

    const unsigned short* gbase[4];
    int lsegoff[4];
#pragma unroll
    for (int i = 0; i < 4; ++i) {
        int s = w * 4 + i;
        int row = (s & 7) * 8 + (lane >> 3);
        int cg = ((lane & 7) ^ (lane >> 3)) * 8;
        if (s < 8) {
            int gm = bm + row;
            if (gm > M - 1) gm = M - 1;
            gbase[i] = A + (size_t)gm * K + cg;
        } else {
            gbase[i] = Bt + (size_t)(bn + row) * K + cg;
        }
        lsegoff[i] = s * 1024;
    }

    auto issue = [&](int tile, int bufoff) {
        int ko = tile << 6;
#pragma unroll
        for (int i = 0; i < 4; ++i)
            __builtin_amdgcn_global_load_lds(
                (const __attribute__((address_space(1))) void*)(gbase[i] + ko),
                (__attribute__((address_space(3))) void*)(smem + bufoff + lsegoff[i]),
                16, 0, 0);
    };
    auto compute = [&](const char* smA) {
        const char* smB = smA + 8192;
#pragma unroll
        for (int ks = 0; ks < 2; ++ks) {
            short8 af[2], bfr[2];
            int cb = ks * 4 + (lane >> 4);
#pragma unroll
            for (int mi = 0; mi < 2; ++mi) {
                int row = wr * 32 + mi * 16 + (lane & 15);
                af[mi] = *(const short8*)(smA + row * 128 + ((cb ^ (row & 7)) << 4));
            }
#pragma unroll
            for (int nj = 0; nj < 2; ++nj) {
                int row = wc * 32 + nj * 16 + (lane & 15);
                bfr[nj] = *(const short8*)(smB + row * 128 + ((cb ^ (row & 7)) << 4));
            }
#pragma unroll
            for (int mi = 0; mi < 2; ++mi)
#pragma unroll
                for (int nj = 0; nj < 2; ++nj)
                    acc[mi][nj] = __builtin_amdgcn_mfma_f32_16x16x32_bf16(
                        af[mi], bfr[nj], acc[mi][nj], 0, 0, 0);
        }
    };

    int nt = K >> 6;
    issue(0, 0);
    __syncthreads();
    for (int tix = 0; tix < nt; ++tix) {
        if (tix + 1 < nt) issue(tix + 1, ((tix + 1) & 1) * 16384);
        compute(smem + (tix & 1) * 16384);
        if (SCALEHALF && tix == 5) {
#pragma unroll
            for (int mi = 0; mi < 2; ++mi)
#pragma unroll
                for (int nj = 0; nj < 2; ++nj)
                    acc[mi][nj] = acc[mi][nj] * inv;
        }
        __syncthreads();
    }

    float* st = (float*)smem;
#pragma unroll
    for (int nj = 0; nj < 2; ++nj) {
        int nl = wc * 32 + nj * 16 + (lane & 15);
        float bs = bias[bn + nl];
#pragma unroll
        for (int mi = 0; mi < 2; ++mi) {
#pragma unroll
            for (int r = 0; r < 4; ++r) {
                int ml = wr * 32 + mi * 16 + (lane >> 4) * 4 + r;
                float v = acc[mi][nj][r] + bs;
                if (GELU) v = gelu_exact(v);
                st[ml * ST_STR + nl] = v;
            }
        }
    }
    __syncthreads();
    if (OUTBF) {
#pragma unroll
        for (int i = 0; i < 2; ++i) {
            int chunk = t + i * 256;
            int ml = chunk >> 3, c8 = (chunk & 7) * 8;
            int m = bm + ml;
            if (m < M) {
                unsigned short tmp[8];
#pragma unroll
                for (int j = 0; j < 8; ++j) tmp[j] = f2bf(st[ml * ST_STR + c8 + j]);
                *(uint4*)((unsigned short*)outp + (size_t)m * N + bn + c8) = *(uint4*)tmp;
            }
        }
    } else {
#pragma unroll
        for (int i = 0; i < 4; ++i) {
            int chunk = t + i * 256;
            int ml = chunk >> 4, c4 = (chunk & 15) * 4;
            int m = bm + ml;
            if (m < M) {
                size_t orow = REMAP ? (size_t)(m + (m >> 11) + 1) : (size_t)m;
                size_t off = orow * (size_t)N + bn + c4;
                float4 v = *(float4*)&st[ml * ST_STR + c4];
                if (RES) {
                    float4 rv = *(const float4*)(res + off);
                    v.x += rv.x; v.y += rv.y; v.z += rv.z; v.w += rv.w;
                }
                *(float4*)((float*)outp + off) = v;
            }
        }
    }
}

// ---------------------------------------------------------------------------
extern "C" void kernel_launch(void* const* d_in, const int* in_sizes, int n_in,
                              void* d_out, int out_size, void* d_ws, size_t ws_size,
                              hipStream_t stream) {
    const float* center  = (const float*)d_in[0];
    const float* x       = (const float*)d_in[1];
    const float* ln1_g   = (const float*)d_in[2];
    const float* ln1_b   = (const float*)d_in[3];
    const float* alpha   = (const float*)d_in[4];
    const float* beta    = (const float*)d_in[5];
    const float* attn_w1 = (const float*)d_in[6];
    const float* attn_b1 = (const float*)d_in[7];
    const float* attn_w2 = (const float*)d_in[8];
    const float* attn_b2 = (const float*)d_in[9];
    const float* ln2_g   = (const float*)d_in[10];
    const float* ln2_b   = (const float*)d_in[11];
    const float* mlp_w1  = (const float*)d_in[12];
    const float* mlp_b1  = (const float*)d_in[13];
    const float* mlp_w2  = (const float*)d_in[14];
    const float* mlp_b2  = (const float*)d_in[15];
    float* out = (float*)d_out;

    // workspace layout (bytes; g overlays dead xn/efp region)
    char* wsb = (char*)d_ws;
    float*          xn     = (float*)(wsb + 0);                  // 12,589,056 (prep->ln2)
    unsigned short* efp    = (unsigned short*)(wsb + 12589056);  // 12,582,912 (knng->gemm1)
    float2*         part   = (float2*)(wsb + 25434112);          // 65,536
    float*          stdbuf = (float*)(wsb + 25499648);           // 256
    float4*         pts4   = (float4*)(wsb + 25499904);          // 131,072
    float*          cv     = (float*)(wsb + 25630976);           // 1,536
    unsigned short* h1     = (unsigned short*)(wsb + 25632512);  // 6,291,456 (gemm1->gemm2)
    unsigned short* yb     = (unsigned short*)(wsb + 31923968);  // 6,294,528 (ln2->gemm3)
    unsigned short* g      = (unsigned short*)(wsb + 0);         // 25,178,112 overlay (gemm3->gemm4)
    unsigned short* w1T    = (unsigned short*)(wsb + 38218496);  // 589,824
    unsigned short* w2T    = (unsigned short*)(wsb + 38808320);  // 294,912
    unsigned short* mw1T   = (unsigned short*)(wsb + 39103232);  // 1,179,648
    unsigned short* mw2T   = (unsigned short*)(wsb + 40282880);  // 1,179,648
    float*          cvpart = (float*)(wsb + 41462528);           // 49,152
    unsigned short* xnb    = (unsigned short*)(wsb + 41511936);  // 6,294,528 (prep->knng)

    // 0. prep: LN1(+bf16) + W1T + transposes + pts4 + cv partials (one grid)
    prep_kernel<<<3857, 256, 0, stream>>>(x, ln1_g, ln1_b, xn, xnb, attn_w1,
                                          attn_w2, mlp_w1, mlp_w2, center, beta,
                                          w1T, w2T, mw1T, mw2T, pts4, cvpart);
    // 1. KNN + gather fused (gather reads bf16 xnb)
    knng_kernel<<<2048, 256, 0, stream>>>(pts4, xnb, alpha, efp, part);
    // 2. std (block 0) + cv reduce (block 1)
    std_kernel<<<2, 256, 0, stream>>>(part, stdbuf, cvpart, attn_b1, cv);
    // 3. h1 = gelu(inv*(ef1@W1a) + ef2@W1b + cv)  M=8192 N=384 K=768
    mfma_gemm<true, false, false, true, true><<<768, 256, 0, stream>>>(
        efp, w1T, cv, nullptr, stdbuf, h1, 8192, 384, 768, 6);
    // 4. out[remap] = x + h1 @ w2T + b2           M=8192 N=384 K=384
    mfma_gemm<false, true, true, false, false><<<768, 256, 0, stream>>>(
        h1, w2T, attn_b2, x, nullptr, out, 8192, 384, 384, 6);
    // 5. LN2 (+cls fusion) -> yb bf16
    ln2_kernel<<<2049, 256, 0, stream>>>(x, xn, out, yb, ln2_g, ln2_b);
    // 6. g = gelu(yb @ mw1T + b1)                 M=8196 N=1536 K=384
    mfma_gemm<true, false, false, true, false><<<3096, 256, 0, stream>>>(
        yb, mw1T, mlp_b1, nullptr, nullptr, g, 8196, 1536, 384, 24);
    // 7. out += g @ mw2T + b2                     M=8196 N=384 K=1536
    mfma_gemm<false, false, true, false, false><<<774, 256, 0, stream>>>(
        g, mw2T, mlp_b2, out, nullptr, out, 8196, 384, 1536, 6);
}

// Round 23
// 123.685 us; speedup vs baseline: 3.3981x; 1.0155x over previous
//
#include <hip/hip_runtime.h>
#include <math.h>

// ---------------------------------------------------------------------------
// Mamba3DBlock forward. B=4, Npts=2048, C=384, K_GROUP=8. x rows = 8196.
// R22: f32 xn deleted — prep's LN1 writes only bf16 xnb (saves 12.6MB HBM
//      writes); LN2 recomputes LN1 for the 4 cls rows directly from x
//      (bit-identical expression). Workspace repacked; g overlay covers
//      only pre-GEMM3-dead buffers.
// ---------------------------------------------------------------------------

#define C384 384

typedef __attribute__((ext_vector_type(8))) short short8;
typedef __attribute__((ext_vector_type(4))) float f32x4;

__device__ __forceinline__ float gelu_exact(float v) {
    return 0.5f * v * (1.0f + erff(v * 0.7071067811865475f));
}

__device__ __forceinline__ unsigned short f2bf(float f) {
    unsigned u = __float_as_uint(f);
    u += 0x7fffu + ((u >> 16) & 1u);
    return (unsigned short)(u >> 16);
}

__device__ __forceinline__ float bf2f(unsigned short b) {
    return __uint_as_float((unsigned)b << 16);
}

// ---------------- prep: LN1(bf16 only) + W1T + transposes + pts4 + cv --------
__global__ __launch_bounds__(256) void prep_kernel(const float* __restrict__ x,
                                                   const float* __restrict__ ln1g,
                                                   const float* __restrict__ ln1b,
                                                   unsigned short* __restrict__ xnb,
                                                   const float* __restrict__ w1,
                                                   const float* __restrict__ w2,
                                                   const float* __restrict__ m1,
                                                   const float* __restrict__ m2,
                                                   const float* __restrict__ center,
                                                   const float* __restrict__ beta,
                                                   unsigned short* __restrict__ o1,
                                                   unsigned short* __restrict__ o2,
                                                   unsigned short* __restrict__ o3,
                                                   unsigned short* __restrict__ o4,
                                                   float4* __restrict__ pts,
                                                   float* __restrict__ cvpart) {
    int tid = blockIdx.x;
    if (tid < 2049) {
        int w = threadIdx.x >> 6, l = threadIdx.x & 63;
        int row = tid * 4 + w;
        const float* xr = x + (size_t)row * C384;
        float v[6];
        float s = 0.f;
#pragma unroll
        for (int i = 0; i < 6; ++i) { v[i] = xr[l + 64 * i]; s += v[i]; }
#pragma unroll
        for (int off = 32; off; off >>= 1) s += __shfl_xor(s, off, 64);
        float m = s * (1.0f / 384.0f);
        float s2 = 0.f;
#pragma unroll
        for (int i = 0; i < 6; ++i) { v[i] -= m; s2 += v[i] * v[i]; }
#pragma unroll
        for (int off = 32; off; off >>= 1) s2 += __shfl_xor(s2, off, 64);
        float rstd = 1.0f / sqrtf(s2 * (1.0f / 384.0f) + 1e-5f);
#pragma unroll
        for (int i = 0; i < 6; ++i) {
            int c = l + 64 * i;
            xnb[(size_t)row * C384 + c] = f2bf(v[i] * rstd * ln1g[c] + ln1b[c]);
        }
    } else if (tid < 2337) {
        // W1 transpose+cast (UNSCALED; inv applied in GEMM1 via SCALEHALF)
        int local = tid - 2049;              // 288 tiles: K=768 x N=384
        int kb = (local / 12) * 32, nb = (local % 12) * 32;
        __shared__ float tile[32][33];
        int c = threadIdx.x & 31, r0 = threadIdx.x >> 5;
#pragma unroll
        for (int i = 0; i < 4; ++i) {
            int r = r0 + i * 8;
            tile[r][c] = w1[(size_t)(kb + r) * 384 + nb + c];
        }
        __syncthreads();
#pragma unroll
        for (int i = 0; i < 4; ++i) {
            int r = r0 + i * 8;
            o1[(size_t)(nb + r) * 768 + kb + c] = f2bf(tile[c][r]);
        }
    } else if (tid < 3633) {
        int local = tid - 2337;
        const float* in; unsigned short* outp; int K, N;
        if (local < 144)      { in = w2; outp = o2; K = 384;  N = 384; }
        else if (local < 720) { in = m1; outp = o3; K = 384;  N = 1536; local -= 144; }
        else                  { in = m2; outp = o4; K = 1536; N = 384;  local -= 720; }
        int ntN = N >> 5;
        int kb = (local / ntN) * 32, nb = (local % ntN) * 32;
        __shared__ float tile[32][33];
        int c = threadIdx.x & 31, r0 = threadIdx.x >> 5;
#pragma unroll
        for (int i = 0; i < 4; ++i) {
            int r = r0 + i * 8;
            tile[r][c] = in[(size_t)(kb + r) * N + nb + c];
        }
        __syncthreads();
#pragma unroll
        for (int i = 0; i < 4; ++i) {
            int r = r0 + i * 8;
            outp[(size_t)(nb + r) * K + kb + c] = f2bf(tile[c][r]);
        }
    } else if (tid < 3665) {
        int p = (tid - 3633) * 256 + threadIdx.x;    // 0..8191
        float cx = center[p * 3], cy = center[p * 3 + 1], cz = center[p * 3 + 2];
        float sq = cx * cx + cy * cy + cz * cz;
        pts[p] = make_float4(cx, cy, cz, sq);
    } else {
        int local = tid - 3665;                      // 0..191
        int nblk = local % 6, ks = local / 6;
        if (threadIdx.x < 64) {
            int n = nblk * 64 + threadIdx.x;
            float s = 0.f;
            int k0 = ks * 24;
#pragma unroll
            for (int j = 0; j < 24; ++j)
                s = fmaf(beta[k0 + j], w1[(size_t)(k0 + j) * 384 + n], s);
            cvpart[(size_t)ks * 384 + n] = s;
        }
    }
}

// ---------------- std (block 0) + cv reduce (block 1) ------------------------
__global__ __launch_bounds__(256) void std_kernel(const float2* __restrict__ part,
                                                  float* __restrict__ stdbuf,
                                                  const float* __restrict__ cvpart,
                                                  const float* __restrict__ b1,
                                                  float* __restrict__ cv) {
    int t = threadIdx.x;
    if (blockIdx.x == 1) {
        for (int n = t; n < 384; n += 256) {
            float s = b1[n];
#pragma unroll
            for (int ks = 0; ks < 32; ++ks) s += cvpart[(size_t)ks * 384 + n];
            cv[n] = s;
        }
        return;
    }
    double s1 = 0.0, s2 = 0.0;
    for (int i = t; i < 8192; i += 256) {
        float2 p = part[i];
        s1 += (double)p.x;
        s2 += (double)p.y;
    }
    __shared__ double r1[256], r2[256];
    r1[t] = s1; r2[t] = s2;
    __syncthreads();
#pragma unroll
    for (int s = 128; s; s >>= 1) {
        if (t < s) { r1[t] += r1[t + s]; r2[t] += r2[t + s]; }
        __syncthreads();
    }
    if (t == 0) {
        const double N = 25165824.0;
        double var = (r2[0] - r1[0] * r1[0] / N) / (N - 1.0);
        float stdf = (float)sqrt(var);
        stdbuf[0] = 1.0f / (stdf + 1e-5f);
    }
}

// ---------------- LN2 (+cls fusion): cls rows recompute LN1 from x -----------
__global__ __launch_bounds__(256) void ln2_kernel(const float* __restrict__ x,
                                                  const float* __restrict__ ln1g,
                                                  const float* __restrict__ ln1b,
                                                  float* __restrict__ out,
                                                  unsigned short* __restrict__ yb,
                                                  const float* __restrict__ gw,
                                                  const float* __restrict__ bw) {
    int w = threadIdx.x >> 6, l = threadIdx.x & 63;
    int row = blockIdx.x * 4 + w;
    float v[6];
    if ((row & 2047) == (row >> 11)) {      // row % 2049 == 0 for row < 4*2049
        // recompute LN1(x_row) (bit-identical to prep's expression), then
        // out = x + xn; feed LN2 from that.
        const float* xr = x + (size_t)row * C384;
        float xv[6];
        float s = 0.f;
#pragma unroll
        for (int i = 0; i < 6; ++i) { xv[i] = xr[l + 64 * i]; s += xv[i]; }
#pragma unroll
        for (int off = 32; off; off >>= 1) s += __shfl_xor(s, off, 64);
        float m = s * (1.0f / 384.0f);
        float s2 = 0.f;
#pragma unroll
        for (int i = 0; i < 6; ++i) { xv[i] -= m; s2 += xv[i] * xv[i]; }
#pragma unroll
        for (int off = 32; off; off >>= 1) s2 += __shfl_xor(s2, off, 64);
        float rstd = 1.0f / sqrtf(s2 * (1.0f / 384.0f) + 1e-5f);
        float* orow = out + (size_t)row * C384;
#pragma unroll
        for (int i = 0; i < 6; ++i) {
            int c = l + 64 * i;
            float xn1 = xv[i] * rstd * ln1g[c] + ln1b[c];
            float o = xr[c] + xn1;
            orow[c] = o;
            v[i] = o;
        }
    } else {
        const float* src = out + (size_t)row * C384;
#pragma unroll
        for (int i = 0; i < 6; ++i) v[i] = src[l + 64 * i];
    }
    float s = 0.f;
#pragma unroll
    for (int i = 0; i < 6; ++i) s += v[i];
#pragma unroll
    for (int off = 32; off; off >>= 1) s += __shfl_xor(s, off, 64);
    float m = s * (1.0f / 384.0f);
    float s2 = 0.f;
#pragma unroll
    for (int i = 0; i < 6; ++i) { v[i] -= m; s2 += v[i] * v[i]; }
#pragma unroll
    for (int off = 32; off; off >>= 1) s2 += __shfl_xor(s2, off, 64);
    float rstd = 1.0f / sqrtf(s2 * (1.0f / 384.0f) + 1e-5f);
#pragma unroll
    for (int i = 0; i < 6; ++i) {
        int c = l + 64 * i;
        yb[(size_t)row * C384 + c] = f2bf(v[i] * rstd * gw[c] + bw[c]);
    }
}

// ---------------- KNN + gather fused: gather reads bf16 xnb ------------------
__global__ __launch_bounds__(256) void knng_kernel(const float4* __restrict__ pts,
                                                   const unsigned short* __restrict__ xnb,
                                                   const float* __restrict__ alpha,
                                                   unsigned short* __restrict__ efp,
                                                   float2* __restrict__ part) {
    int w = threadIdx.x >> 6;
    int l = threadIdx.x & 63;
    int q = blockIdx.x * 4 + w;
    int b = q >> 11, n = q & 2047;
    __shared__ int sidx[4][8];
    {
        const float4* pb = pts + (size_t)b * 2048;
        float4 qp = pb[n];
        float sqq = qp.w;
        unsigned val[32];
        unsigned long long gv[8];
#pragma unroll
        for (int g = 0; g < 8; ++g) {
            unsigned long long kmin = ~0ULL;
#pragma unroll
            for (int j = 0; j < 4; ++j) {
                int i = g * 4 + j;
                float4 c = pb[i * 64 + l];
                float dot = qp.x * c.x + qp.y * c.y + qp.z * c.z;
                float d2 = (sqq + c.w) - 2.0f * dot;
                unsigned u = __float_as_uint(d2);
                u ^= (unsigned)(((int)u >> 31) | 0x80000000);
                val[i] = u;
                unsigned long long kk = ((unsigned long long)u << 32) | (unsigned)i;
                kmin = kk < kmin ? kk : kmin;
            }
            gv[g] = kmin;
        }
        unsigned long long lm = gv[0];
#pragma unroll
        for (int g = 1; g < 8; ++g) lm = gv[g] < lm ? gv[g] : lm;

        for (int sel = 0; sel < 8; ++sel) {
            unsigned wval = (unsigned)(lm >> 32);
            unsigned wmin = wval;
#pragma unroll
            for (int off = 32; off; off >>= 1) {
                unsigned o = (unsigned)__shfl_xor((int)wmin, off, 64);
                wmin = o < wmin ? o : wmin;
            }
            bool eligible = (wval == wmin);
            unsigned long long mask = __ballot(eligible);
            unsigned myM = ((unsigned)lm) * 64u + (unsigned)l;
            if (__popcll(mask) > 1) {
                unsigned mc = eligible ? myM : 0xFFFFFFFFu;
#pragma unroll
                for (int off = 32; off; off >>= 1) {
                    unsigned o = (unsigned)__shfl_xor((int)mc, off, 64);
                    mc = o < mc ? o : mc;
                }
                eligible = eligible && (myM == mc);
            }
            if (eligible) {
                sidx[w][sel] = (int)myM;
                unsigned ws = (unsigned)lm;
#pragma unroll
                for (int g = 0; g < 8; ++g) {
                    if (gv[g] == lm) {
                        asm volatile("" ::: "memory");
                        unsigned long long kmin = ~0ULL;
#pragma unroll
                        for (int j = 0; j < 4; ++j) {
                            int i = g * 4 + j;
                            unsigned v = ((unsigned)i == ws) ? 0xFFFFFFFFu : val[i];
                            val[i] = v;
                            unsigned long long kk = ((unsigned long long)v << 32) | (unsigned)i;
                            kmin = kk < kmin ? kk : kmin;
                        }
                        gv[g] = kmin;
                    }
                }
                unsigned long long nlm = gv[0];
#pragma unroll
                for (int g = 1; g < 8; ++g) nlm = gv[g] < nlm ? gv[g] : nlm;
                lm = nlm;
            }
        }
    }
    // gather phase (bf16 reads; math in f32)
    const unsigned short* xno = xnb + ((size_t)b * 2049 + 1) * C384;
    const unsigned short* xc  = xnb + ((size_t)q + b + 1) * C384;
    int i0 = sidx[w][0], i1 = sidx[w][1], i2 = sidx[w][2], i3 = sidx[w][3];
    int i4 = sidx[w][4], i5 = sidx[w][5], i6 = sidx[w][6], i7 = sidx[w][7];
    float s1 = 0.f, s2 = 0.f;
#pragma unroll
    for (int ci = 0; ci < 6; ++ci) {
        int c = l + ci * 64;
        float xcv = bf2f(xc[c]);
        float v0 = bf2f(xno[(size_t)i0 * C384 + c]), v1 = bf2f(xno[(size_t)i1 * C384 + c]);
        float v2 = bf2f(xno[(size_t)i2 * C384 + c]), v3 = bf2f(xno[(size_t)i3 * C384 + c]);
        float v4 = bf2f(xno[(size_t)i4 * C384 + c]), v5 = bf2f(xno[(size_t)i5 * C384 + c]);
        float v6 = bf2f(xno[(size_t)i6 * C384 + c]), v7 = bf2f(xno[(size_t)i7 * C384 + c]);
        float acc = ((v0 + v1) + (v2 + v3)) + ((v4 + v5) + (v6 + v7));
        float d;
        d = v0 - xcv; s1 += d; s2 += d * d;
        d = v1 - xcv; s1 += d; s2 += d * d;
        d = v2 - xcv; s1 += d; s2 += d * d;
        d = v3 - xcv; s1 += d; s2 += d * d;
        d = v4 - xcv; s1 += d; s2 += d * d;
        d = v5 - xcv; s1 += d; s2 += d * d;
        d = v6 - xcv; s1 += d; s2 += d * d;
        d = v7 - xcv; s1 += d; s2 += d * d;
        float mk = acc * 0.125f;
        efp[(size_t)q * 768 + c]       = f2bf(alpha[c] * (mk - xcv));
        efp[(size_t)q * 768 + 384 + c] = f2bf(alpha[384 + c] * xcv);
    }
#pragma unroll
    for (int off = 32; off; off >>= 1) {
        s1 += __shfl_xor(s1, off, 64);
        s2 += __shfl_xor(s2, off, 64);
    }
    if (l == 0) part[q] = make_float2(s1, s2);
}

// ---------------- bf16 MFMA GEMM, 64x64 tile, BK=64, global_load_lds ---------
// SCALEHALF: after K-tile 5 (k<384 accumulated), scale acc by inv=stdbuf[0].
#define ST_STR 68

template <bool GELU, bool REMAP, bool RES, bool OUTBF, bool SCALEHALF>
__global__ __launch_bounds__(256) void mfma_gemm(const unsigned short* __restrict__ A,
                                                 const unsigned short* __restrict__ Bt,
                                                 const float* __restrict__ bias,
                                                 const float* __restrict__ res,
                                                 const float* __restrict__ sb,
                                                 void* __restrict__ outp,
                                                 int M, int N, int K, int ntn) {
    __shared__ char smem[32768];   // 2 bufs x (A 8K | B 8K)
    int t = threadIdx.x;
    int lane = t & 63, w = t >> 6;
    int wr = w >> 1, wc = w & 1;

    int nwg = gridDim.x;
    int q8 = nwg >> 3, r8 = nwg & 7;
    int xcd = blockIdx.x & 7, idx = blockIdx.x >> 3;
    int lid = (xcd < r8 ? xcd * (q8 + 1) : r8 * (q8 + 1) + (xcd - r8) * q8) + idx;
    int by = lid / ntn, bx = lid - by * ntn;
    int bm = by * 64, bn = bx * 64;

    float inv = SCALEHALF ? sb[0] : 1.0f;

    f32x4 acc[2][2] = {};

    const unsigned short* gbase[4];
    int lsegoff[4];
#pragma unroll
    for (int i = 0; i < 4; ++i) {
        int s = w * 4 + i;
        int row = (s & 7) * 8 + (lane >> 3);
        int cg = ((lane & 7) ^ (lane >> 3)) * 8;
        if (s < 8) {
            int gm = bm + row;
            if (gm > M - 1) gm = M - 1;
            gbase[i] = A + (size_t)gm * K + cg;
        } else {
            gbase[i] = Bt + (size_t)(bn + row) * K + cg;
        }
        lsegoff[i] = s * 1024;
    }

    auto issue = [&](int tile, int bufoff) {
        int ko = tile << 6;
#pragma unroll
        for (int i = 0; i < 4; ++i)
            __builtin_amdgcn_global_load_lds(
                (const __attribute__((address_space(1))) void*)(gbase[i] + ko),
                (__attribute__((address_space(3))) void*)(smem + bufoff + lsegoff[i]),
                16, 0, 0);
    };
    auto compute = [&](const char* smA) {
        const char* smB = smA + 8192;
#pragma unroll
        for (int ks = 0; ks < 2; ++ks) {
            short8 af[2], bfr[2];
            int cb = ks * 4 + (lane >> 4);
#pragma unroll
            for (int mi = 0; mi < 2; ++mi) {
                int row = wr * 32 + mi * 16 + (lane & 15);
                af[mi] = *(const short8*)(smA + row * 128 + ((cb ^ (row & 7)) << 4));
            }
#pragma unroll
            for (int nj = 0; nj < 2; ++nj) {
                int row = wc * 32 + nj * 16 + (lane & 15);
                bfr[nj] = *(const short8*)(smB + row * 128 + ((cb ^ (row & 7)) << 4));
            }
#pragma unroll
            for (int mi = 0; mi < 2; ++mi)
#pragma unroll
                for (int nj = 0; nj < 2; ++nj)
                    acc[mi][nj] = __builtin_amdgcn_mfma_f32_16x16x32_bf16(
                        af[mi], bfr[nj], acc[mi][nj], 0, 0, 0);
        }
    };

    int nt = K >> 6;
    issue(0, 0);
    __syncthreads();
    for (int tix = 0; tix < nt; ++tix) {
        if (tix + 1 < nt) issue(tix + 1, ((tix + 1) & 1) * 16384);
        compute(smem + (tix & 1) * 16384);
        if (SCALEHALF && tix == 5) {
#pragma unroll
            for (int mi = 0; mi < 2; ++mi)
#pragma unroll
                for (int nj = 0; nj < 2; ++nj)
                    acc[mi][nj] = acc[mi][nj] * inv;
        }
        __syncthreads();
    }

    float* st = (float*)smem;
#pragma unroll
    for (int nj = 0; nj < 2; ++nj) {
        int nl = wc * 32 + nj * 16 + (lane & 15);
        float bs = bias[bn + nl];
#pragma unroll
        for (int mi = 0; mi < 2; ++mi) {
#pragma unroll
            for (int r = 0; r < 4; ++r) {
                int ml = wr * 32 + mi * 16 + (lane >> 4) * 4 + r;
                float v = acc[mi][nj][r] + bs;
                if (GELU) v = gelu_exact(v);
                st[ml * ST_STR + nl] = v;
            }
        }
    }
    __syncthreads();
    if (OUTBF) {
#pragma unroll
        for (int i = 0; i < 2; ++i) {
            int chunk = t + i * 256;
            int ml = chunk >> 3, c8 = (chunk & 7) * 8;
            int m = bm + ml;
            if (m < M) {
                unsigned short tmp[8];
#pragma unroll
                for (int j = 0; j < 8; ++j) tmp[j] = f2bf(st[ml * ST_STR + c8 + j]);
                *(uint4*)((unsigned short*)outp + (size_t)m * N + bn + c8) = *(uint4*)tmp;
            }
        }
    } else {
#pragma unroll
        for (int i = 0; i < 4; ++i) {
            int chunk = t + i * 256;
            int ml = chunk >> 4, c4 = (chunk & 15) * 4;
            int m = bm + ml;
            if (m < M) {
                size_t orow = REMAP ? (size_t)(m + (m >> 11) + 1) : (size_t)m;
                size_t off = orow * (size_t)N + bn + c4;
                float4 v = *(float4*)&st[ml * ST_STR + c4];
                if (RES) {
                    float4 rv = *(const float4*)(res + off);
                    v.x += rv.x; v.y += rv.y; v.z += rv.z; v.w += rv.w;
                }
                *(float4*)((float*)outp + off) = v;
            }
        }
    }
}

// ---------------------------------------------------------------------------
extern "C" void kernel_launch(void* const* d_in, const int* in_sizes, int n_in,
                              void* d_out, int out_size, void* d_ws, size_t ws_size,
                              hipStream_t stream) {
    const float* center  = (const float*)d_in[0];
    const float* x       = (const float*)d_in[1];
    const float* ln1_g   = (const float*)d_in[2];
    const float* ln1_b   = (const float*)d_in[3];
    const float* alpha   = (const float*)d_in[4];
    const float* beta    = (const float*)d_in[5];
    const float* attn_w1 = (const float*)d_in[6];
    const float* attn_b1 = (const float*)d_in[7];
    const float* attn_w2 = (const float*)d_in[8];
    const float* attn_b2 = (const float*)d_in[9];
    const float* ln2_g   = (const float*)d_in[10];
    const float* ln2_b   = (const float*)d_in[11];
    const float* mlp_w1  = (const float*)d_in[12];
    const float* mlp_b1  = (const float*)d_in[13];
    const float* mlp_w2  = (const float*)d_in[14];
    const float* mlp_b2  = (const float*)d_in[15];
    float* out = (float*)d_out;

    // workspace layout (bytes). g overlay [0, 25,178,112) covers only buffers
    // dead before GEMM3: xnb (knng), efp (gemm1), part/stdbuf/pts4/cv (gemm1),
    // h1 (gemm2). yb and weights live past the overlay.
    char* wsb = (char*)d_ws;
    unsigned short* xnb    = (unsigned short*)(wsb + 0);         // 6,294,528
    unsigned short* efp    = (unsigned short*)(wsb + 6294528);   // 12,582,912 -> 18,877,440
    float2*         part   = (float2*)(wsb + 18877440);          // 65,536
    float*          stdbuf = (float*)(wsb + 18942976);           // 256
    float4*         pts4   = (float4*)(wsb + 18943232);          // 131,072
    float*          cv     = (float*)(wsb + 19074304);           // 1,536
    unsigned short* h1     = (unsigned short*)(wsb + 19075840);  // 6,291,456 -> 25,367,296
    unsigned short* g      = (unsigned short*)(wsb + 0);         // 25,178,112 overlay
    unsigned short* yb     = (unsigned short*)(wsb + 25367296);  // 6,294,528 -> 31,661,824
    unsigned short* w1T    = (unsigned short*)(wsb + 31661824);  // 589,824
    unsigned short* w2T    = (unsigned short*)(wsb + 32251648);  // 294,912
    unsigned short* mw1T   = (unsigned short*)(wsb + 32546560);  // 1,179,648
    unsigned short* mw2T   = (unsigned short*)(wsb + 33726208);  // 1,179,648
    float*          cvpart = (float*)(wsb + 34905856);           // 49,152

    // 0. prep: LN1(bf16) + W1T + transposes + pts4 + cv partials (one grid)
    prep_kernel<<<3857, 256, 0, stream>>>(x, ln1_g, ln1_b, xnb, attn_w1,
                                          attn_w2, mlp_w1, mlp_w2, center, beta,
                                          w1T, w2T, mw1T, mw2T, pts4, cvpart);
    // 1. KNN + gather fused (gather reads bf16 xnb)
    knng_kernel<<<2048, 256, 0, stream>>>(pts4, xnb, alpha, efp, part);
    // 2. std (block 0) + cv reduce (block 1)
    std_kernel<<<2, 256, 0, stream>>>(part, stdbuf, cvpart, attn_b1, cv);
    // 3. h1 = gelu(inv*(ef1@W1a) + ef2@W1b + cv)  M=8192 N=384 K=768
    mfma_gemm<true, false, false, true, true><<<768, 256, 0, stream>>>(
        efp, w1T, cv, nullptr, stdbuf, h1, 8192, 384, 768, 6);
    // 4. out[remap] = x + h1 @ w2T + b2           M=8192 N=384 K=384
    mfma_gemm<false, true, true, false, false><<<768, 256, 0, stream>>>(
        h1, w2T, attn_b2, x, nullptr, out, 8192, 384, 384, 6);
    // 5. LN2 (+cls-row LN1 recompute from x) -> yb bf16
    ln2_kernel<<<2049, 256, 0, stream>>>(x, ln1_g, ln1_b, out, yb, ln2_g, ln2_b);
    // 6. g = gelu(yb @ mw1T + b1)                 M=8196 N=1536 K=384
    mfma_gemm<true, false, false, true, false><<<3096, 256, 0, stream>>>(
        yb, mw1T, mlp_b1, nullptr, nullptr, g, 8196, 1536, 384, 24);
    // 7. out += g @ mw2T + b2                     M=8196 N=384 K=1536
    mfma_gemm<false, false, true, false, false><<<774, 256, 0, stream>>>(
        g, mw2T, mlp_b2, out, nullptr, out, 8196, 384, 1536, 6);
}